// Round 11
// baseline (300.119 us; speedup 1.0000x reference)
//
#include <hip/hip_runtime.h>

#define N_NODES 50000
#define N_EDGES 800000
#define ET (N_EDGES + N_NODES)   // edges + self loops = 850000
#define MID 129
#define OUTC 6
#define NB 196                   // coarse buckets: dst >> 8
#define CT 4096                  // edges per coarse-scatter block

typedef _Float16 half2v __attribute__((ext_vector_type(2)));
typedef _Float16 half8  __attribute__((ext_vector_type(8)));
typedef float    floatx4 __attribute__((ext_vector_type(4)));

__device__ __forceinline__ float lrelu(float x) { return fmaxf(x, 0.2f * x); }

// ---------------- CSR build: two-phase bin sort ----------------

__global__ void ccount_kernel(const int* __restrict__ dst, int* __restrict__ ccnt) {
    __shared__ int lh[NB];
    for (int i = threadIdx.x; i < NB; i += 256) lh[i] = 0;
    __syncthreads();
    int base = blockIdx.x * CT;
#pragma unroll 4
    for (int j = 0; j < CT; j += 256) {
        int e = base + j + threadIdx.x;
        if (e < ET) {
            int d = (e < N_EDGES) ? dst[e] : (e - N_EDGES);
            atomicAdd(&lh[d >> 8], 1);
        }
    }
    __syncthreads();
    for (int i = threadIdx.x; i < NB; i += 256) {
        int v = lh[i];
        if (v) atomicAdd(&ccnt[i], v);
    }
}

__global__ void cscan_kernel(const int* __restrict__ ccnt, int* __restrict__ cbase,
                             int* __restrict__ ccur) {
    __shared__ int buf[256];
    int t = threadIdx.x;
    buf[t] = (t < NB) ? ccnt[t] : 0;
    __syncthreads();
    for (int off = 1; off < 256; off <<= 1) {
        int v = (t >= off) ? buf[t - off] : 0;
        __syncthreads();
        buf[t] += v;
        __syncthreads();
    }
    int excl = t ? buf[t - 1] : 0;
    if (t < NB) { cbase[t] = excl; ccur[t] = excl; }
    if (t == NB - 1) cbase[NB] = buf[t];
}

__global__ void cscatter_kernel(const int* __restrict__ src, const int* __restrict__ dst,
                                int* __restrict__ ccur, unsigned int* __restrict__ cval) {
    __shared__ unsigned int staged[CT];
    __shared__ int lh[NB], lex[NB], lcur[NB], lgb[NB];
    __shared__ int sbuf[256];
    int tid = threadIdx.x;
    for (int i = tid; i < NB; i += 256) lh[i] = 0;
    __syncthreads();
    int base = blockIdx.x * CT;
    unsigned int myv[16];
    int myb[16];
    int myn = 0;
#pragma unroll
    for (int j = 0; j < 16; ++j) {
        int e = base + j * 256 + tid;
        if (e < ET) {
            int s, d;
            if (e < N_EDGES) { s = src[e]; d = dst[e]; }
            else             { s = d = e - N_EDGES; }
            int b = d >> 8;
            myv[j] = ((unsigned)b << 24) | ((unsigned)(d & 255) << 16) | (unsigned)s;
            myb[j] = b;
            atomicAdd(&lh[b], 1);
            myn = j + 1;
        }
    }
    __syncthreads();
    sbuf[tid] = (tid < NB) ? lh[tid] : 0;
    __syncthreads();
    for (int off = 1; off < 256; off <<= 1) {
        int v = (tid >= off) ? sbuf[tid - off] : 0;
        __syncthreads();
        sbuf[tid] += v;
        __syncthreads();
    }
    if (tid < NB) {
        int excl = tid ? sbuf[tid - 1] : 0;
        lex[tid] = excl;
        lcur[tid] = excl;
    }
    __syncthreads();
    for (int j = 0; j < myn; ++j) {
        int p = atomicAdd(&lcur[myb[j]], 1);
        staged[p] = myv[j];
    }
    __syncthreads();
    if (tid < NB) {
        int c = lh[tid];
        lgb[tid] = c ? atomicAdd(&ccur[tid], c) : 0;
    }
    __syncthreads();
    int tot = ET - base; if (tot > CT) tot = CT;
    for (int i = tid; i < tot; i += 256) {
        unsigned int v = staged[i];
        int b = v >> 24;
        cval[lgb[b] + (i - lex[b])] = v;
    }
}

__global__ __launch_bounds__(512)
void fine_kernel(const unsigned int* __restrict__ cval, const int* __restrict__ cbase,
                 int* __restrict__ rowp, unsigned short* __restrict__ csr_src) {
    __shared__ int h[256], cur[256], sb[256];
    int b = blockIdx.x;
    int beg = cbase[b], end = cbase[b + 1];
    int t = threadIdx.x;
    if (t < 256) h[t] = 0;
    __syncthreads();
    for (int i = beg + t; i < end; i += 512)
        atomicAdd(&h[(cval[i] >> 16) & 255], 1);
    __syncthreads();
    if (t < 256) sb[t] = h[t];
    __syncthreads();
    for (int off = 1; off < 256; off <<= 1) {
        int v = 0;
        if (t < 256 && t >= off) v = sb[t - off];
        __syncthreads();
        if (t < 256) sb[t] += v;
        __syncthreads();
    }
    if (t < 256) {
        int excl = t ? sb[t - 1] : 0;
        cur[t] = excl;
        int dstv = (b << 8) + t;
        if (dstv <= N_NODES) rowp[dstv] = beg + excl;
    }
    __syncthreads();
    for (int i = beg + t; i < end; i += 512) {
        unsigned int v = cval[i];
        int low = (v >> 16) & 255;
        int p = atomicAdd(&cur[low], 1);
        csr_src[beg + p] = (unsigned short)(v & 0xFFFFu);
    }
}

// ---- Build MFMA weight blocks: Wt[l][144][128] fp16 (n-major, k-minor) ----
__global__ void padw_kernel(const float* __restrict__ W0, const float* __restrict__ a0s,
                            const float* __restrict__ a0d, const float* __restrict__ W1,
                            const float* __restrict__ a1s, const float* __restrict__ a1d,
                            _Float16* __restrict__ Wt0, _Float16* __restrict__ Wt1,
                            float* __restrict__ w128row1) {
    const int SEG = 144 * 128;
    int i = blockIdx.x * blockDim.x + threadIdx.x;
    if (i < 2 * SEG) {
        int l = i / SEG;
        int ii = i - l * SEG;
        int n = ii >> 7, k = ii & 127;
        const float* W = l ? W1 : W0;
        const float* as = l ? a1s : a0s;
        const float* ad = l ? a1d : a0d;
        float v = 0.f;
        if (n < 129) v = W[k * MID + n];
        else if (n < 132) {
            int h = n - 129;
            float sum = 0.f;
            for (int c = 0; c < 43; ++c) sum += W[k * MID + 43 * h + c] * as[43 * h + c];
            v = sum;
        } else if (n < 135) {
            int h = n - 132;
            float sum = 0.f;
            for (int c = 0; c < 43; ++c) sum += W[k * MID + 43 * h + c] * ad[43 * h + c];
            v = sum;
        }
        (l ? Wt1 : Wt0)[ii] = (_Float16)v;
    } else if (i < 2 * SEG + 144) {
        int n = i - 2 * SEG;
        float v = 0.f;
        if (n < 129) v = W1[128 * MID + n];
        else if (n < 132) {
            int h = n - 129;
            float sum = 0.f;
            for (int c = 0; c < 43; ++c) sum += W1[128 * MID + 43 * h + c] * a1s[43 * h + c];
            v = sum;
        } else if (n < 135) {
            int h = n - 132;
            float sum = 0.f;
            for (int c = 0; c < 43; ++c) sum += W1[128 * MID + 43 * h + c] * a1d[43 * h + c];
            v = sum;
        }
        w128row1[n] = v;
    }
}

// ---------------- MFMA GEMM + fused logits ----------------
template <bool SRC32, bool RANK1>
__global__ __launch_bounds__(256)
void gemm_mfma_kernel(const float* __restrict__ X32, const _Float16* __restrict__ Xh,
                      const float* __restrict__ Xl,
                      const _Float16* __restrict__ Wt, const float* __restrict__ w128,
                      _Float16* __restrict__ Hm16, float* __restrict__ Hl,
                      float* __restrict__ al, float* __restrict__ ar) {
    int wave = threadIdx.x >> 6, lane = threadIdx.x & 63;
    int mt = blockIdx.x * 4 + wave;
    if (mt * 16 >= N_NODES) return;
    int t = lane & 15, quad = lane >> 4;
    int row0 = mt * 16;

    half8 af[4];
    if (SRC32) {
        const float* arow = X32 + ((size_t)(row0 + t) << 7) + quad * 8;
#pragma unroll
        for (int kt = 0; kt < 4; ++kt) {
            float4 a0 = *(const float4*)(arow + kt * 32);
            float4 a1 = *(const float4*)(arow + kt * 32 + 4);
            half8 h;
            h[0] = (_Float16)a0.x; h[1] = (_Float16)a0.y;
            h[2] = (_Float16)a0.z; h[3] = (_Float16)a0.w;
            h[4] = (_Float16)a1.x; h[5] = (_Float16)a1.y;
            h[6] = (_Float16)a1.z; h[7] = (_Float16)a1.w;
            af[kt] = h;
        }
    } else {
        const _Float16* arow = Xh + ((size_t)(row0 + t) << 7) + quad * 8;
#pragma unroll
        for (int kt = 0; kt < 4; ++kt) af[kt] = *(const half8*)(arow + kt * 32);
    }

    floatx4 acc[3];
#pragma unroll
    for (int nt = 0; nt < 3; ++nt) {
        int ntile = blockIdx.y * 3 + nt;
        const _Float16* brow = Wt + ((size_t)(ntile * 16 + t) << 7) + quad * 8;
        floatx4 a = {0.f, 0.f, 0.f, 0.f};
#pragma unroll
        for (int kt = 0; kt < 4; ++kt) {
            half8 b = *(const half8*)(brow + kt * 32);
            a = __builtin_amdgcn_mfma_f32_16x16x32_f16(af[kt], b, a, 0, 0, 0);
        }
        acc[nt] = a;
    }

#pragma unroll
    for (int r = 0; r < 4; ++r) {
        int row = row0 + quad * 4 + r;
        float xl = RANK1 ? Xl[row] : 0.f;
#pragma unroll
        for (int nt = 0; nt < 3; ++nt) {
            int n = (blockIdx.y * 3 + nt) * 16 + t;
            float v = acc[nt][r];
            if (RANK1) v += xl * w128[n];
            if (n < 128) {
                Hm16[((size_t)row << 7) + n] = (_Float16)v;
            } else if (n == 128) {
                Hl[row] = v;
            } else if (n < 132) {
                al[row * 3 + (n - 129)] = v;
            } else if (n < 135) {
                ar[row * 3 + (n - 132)] = v;
            }
        }
    }
}

// ------- fused softmax + aggregation (129 ch, 3 heads), 4 edges/iter -------
// float4 LDS (conflict-free b128); per-edge fp16 pack (cvt_pkrtz) + v_perm weight select
// + v_fma_mix accumulate. L2EPI: layer-2 node GEMM fused into epilogue.
template <bool ACT, bool L2EPI>
__global__ void agg129_kernel(const _Float16* __restrict__ Hm16, const float* __restrict__ Hl,
                              const float* __restrict__ al, const float* __restrict__ ar,
                              const int* __restrict__ rowp, const unsigned short* __restrict__ srcs,
                              const float* __restrict__ bias, _Float16* __restrict__ Omh,
                              float* __restrict__ Ol,
                              const float* __restrict__ W2, const float* __restrict__ a2s,
                              const float* __restrict__ a2d, float* __restrict__ H2,
                              float* __restrict__ al2, float* __restrict__ ar2) {
    __shared__ float4 exs[4][64];
    int lane = threadIdx.x & 63;
    int wv   = threadIdx.x >> 6;
    int wid  = blockIdx.x * 4 + wv;
    if (wid >= N_NODES) return;

    int beg = rowp[wid], end = rowp[wid + 1];
    float ard0 = ar[wid * 3], ard1 = ar[wid * 3 + 1], ard2 = ar[wid * 3 + 2];

    int g  = lane >> 4;        // edge within quad
    int q  = lane & 15;        // channel group: channels 8q..8q+7
    int cb = 8 * q;

    bool bm0[8], bm1[8];
#pragma unroll
    for (int j = 0; j < 8; ++j) {
        bm0[j] = (cb + j) < 43;
        bm1[j] = (cb + j) < 86;
    }
    // v_perm selectors (HW-verified in R9): bytes 4..7 = arg0 (e0|e1), bytes 0..3 = arg1 (e2|-)
    unsigned selv[4];
#pragma unroll
    for (int p = 0; p < 4; ++p) {
        int c0 = cb + 2 * p, c1 = c0 + 1;
        int l0 = (c0 < 43) ? 4 : (c0 < 86) ? 6 : 0;
        int l1 = (c1 < 43) ? 4 : (c1 < 86) ? 6 : 0;
        selv[p] = (unsigned)l0 | ((unsigned)(l0 + 1) << 8) |
                  ((unsigned)l1 << 16) | ((unsigned)(l1 + 1) << 24);
    }

    float accv[8];
#pragma unroll
    for (int j = 0; j < 8; ++j) accv[j] = 0.f;
    float acc128 = 0.f;
    float s0 = 0.f, s1 = 0.f, s2 = 0.f;
    float4* exw = exs[wv];

    for (int base = beg; base < end; base += 64) {
        int i = base + lane;
        float e0 = 0.f, e1 = 0.f, e2 = 0.f;
        int s = 0;
        if (i < end) {
            s = (int)srcs[i];
            const float* ap = al + s * 3;
            e0 = __expf(lrelu(ap[0] + ard0));
            e1 = __expf(lrelu(ap[1] + ard1));
            e2 = __expf(lrelu(ap[2] + ard2));
            s0 += e0; s1 += e1; s2 += e2;
        }
        exw[lane] = make_float4(e0, e1, e2, __int_as_float(s));
        int cnt = end - base; if (cnt > 64) cnt = 64;
        for (int tt = 0; tt < cnt; tt += 4) {
            float4 ed = exw[tt + g];             // zero-filled beyond cnt -> safe
            int ss = __float_as_int(ed.w);
            half8 hv = *(const half8*)(Hm16 + ((size_t)ss << 7) + cb);
            unsigned p01 = __builtin_bit_cast(unsigned, __builtin_amdgcn_cvt_pkrtz(ed.x, ed.y));
            unsigned p2z = __builtin_bit_cast(unsigned, __builtin_amdgcn_cvt_pkrtz(ed.z, ed.z));
            if (q == 0) acc128 += ed.z * Hl[ss];
#pragma unroll
            for (int p = 0; p < 4; ++p) {
                unsigned wp = __builtin_amdgcn_perm(p01, p2z, selv[p]);
                half2v w2 = __builtin_bit_cast(half2v, wp);
                accv[2 * p]     += (float)w2[0] * (float)hv[2 * p];
                accv[2 * p + 1] += (float)w2[1] * (float)hv[2 * p + 1];
            }
        }
    }
#pragma unroll
    for (int off = 16; off <= 32; off <<= 1) {
#pragma unroll
        for (int j = 0; j < 8; ++j) accv[j] += __shfl_xor(accv[j], off, 64);
        acc128 += __shfl_xor(acc128, off, 64);
    }
#pragma unroll
    for (int off = 32; off; off >>= 1) {
        s0 += __shfl_xor(s0, off, 64);
        s1 += __shfl_xor(s1, off, 64);
        s2 += __shfl_xor(s2, off, 64);
    }
    float d0 = 1.f / (s0 + 1e-16f);
    float d1 = 1.f / (s1 + 1e-16f);
    float d2 = 1.f / (s2 + 1e-16f);
    if (g == 0) {   // lanes 0..15
        float4 bv0 = *(const float4*)(bias + cb);
        float4 bv1 = *(const float4*)(bias + cb + 4);
        float bb[8] = {bv0.x, bv0.y, bv0.z, bv0.w, bv1.x, bv1.y, bv1.z, bv1.w};
        float o[8];
#pragma unroll
        for (int j = 0; j < 8; ++j) {
            float dv = bm0[j] ? d0 : (bm1[j] ? d1 : d2);
            o[j] = accv[j] * dv + bb[j];
            if (ACT) o[j] = lrelu(o[j]);
        }
        float o128 = 0.f;
        if (lane == 0) {
            o128 = acc128 * d2 + bias[128];
            if (ACT) o128 = lrelu(o128);
        }
        if (!L2EPI) {
            half8 oh;
#pragma unroll
            for (int j = 0; j < 8; ++j) oh[j] = (_Float16)o[j];
            *(half8*)(Omh + ((size_t)wid << 7) + cb) = oh;
            if (lane == 0) Ol[wid] = o128;
        } else {
            float pr[OUTC];
#pragma unroll
            for (int c = 0; c < OUTC; ++c) pr[c] = 0.f;
#pragma unroll
            for (int j = 0; j < 8; ++j) {
                const float* wr = W2 + (cb + j) * OUTC;
                float ov = o[j];
#pragma unroll
                for (int c = 0; c < OUTC; ++c) pr[c] += ov * wr[c];
            }
            if (lane == 0) {
#pragma unroll
                for (int c = 0; c < OUTC; ++c) pr[c] += o128 * W2[128 * OUTC + c];
            }
#pragma unroll
            for (int off = 1; off < 16; off <<= 1)
#pragma unroll
                for (int c = 0; c < OUTC; ++c) pr[c] += __shfl_xor(pr[c], off, 64);
            if (lane == 0) {
                float sl = 0.f, sr = 0.f;
#pragma unroll
                for (int c = 0; c < OUTC; ++c) {
                    H2[wid * OUTC + c] = pr[c];
                    sl += pr[c] * a2s[c];
                    sr += pr[c] * a2d[c];
                }
                al2[wid] = sl;
                ar2[wid] = sr;
            }
        }
    }
}

// ---------------- layer 2 aggregate (1 head, 6 ch), 8 edges/iter ----------------
__global__ void agg6_kernel(const float* __restrict__ H2, const float* __restrict__ al2,
                            const float* __restrict__ ar2, const int* __restrict__ rowp,
                            const unsigned short* __restrict__ srcs, const float* __restrict__ b2,
                            float* __restrict__ out) {
    __shared__ float2 exs[4][64];
    int lane = threadIdx.x & 63;
    int wv   = threadIdx.x >> 6;
    int wid  = blockIdx.x * 4 + wv;
    if (wid >= N_NODES) return;
    int beg = rowp[wid], end = rowp[wid + 1];
    float ard = ar2[wid];
    int grp = lane >> 3;
    int myc = lane & 7;
    int cc  = (myc < OUTC) ? myc : 0;
    float ssum = 0.f, acc = 0.f;
    float2* exw = exs[wv];
    for (int base = beg; base < end; base += 64) {
        int i = base + lane;
        float ex = 0.f;
        int s = 0;
        if (i < end) {
            s = (int)srcs[i];
            ex = __expf(lrelu(al2[s] + ard));
            ssum += ex;
        }
        exw[lane] = make_float2(ex, __int_as_float(s));
        int cnt = end - base; if (cnt > 64) cnt = 64;
        for (int t = 0; t < cnt; t += 8) {
            float2 ed = exw[t + grp];
            int ss = __float_as_int(ed.y);
            acc += ed.x * H2[ss * OUTC + cc];
        }
    }
    acc += __shfl_xor(acc, 8, 64);
    acc += __shfl_xor(acc, 16, 64);
    acc += __shfl_xor(acc, 32, 64);
#pragma unroll
    for (int off = 32; off; off >>= 1) ssum += __shfl_xor(ssum, off, 64);
    float dinv = 1.f / (ssum + 1e-16f);
    if (lane < OUTC) out[(size_t)wid * OUTC + lane] = acc * dinv + b2[lane];
}

// ---------------- launch ----------------

extern "C" void kernel_launch(void* const* d_in, const int* in_sizes, int n_in,
                              void* d_out, int out_size, void* d_ws, size_t ws_size,
                              hipStream_t stream) {
    const float* x   = (const float*)d_in[0];
    const int*   ei  = (const int*)d_in[1];
    const float* W0  = (const float*)d_in[2];
    const float* a0s = (const float*)d_in[3];
    const float* a0d = (const float*)d_in[4];
    const float* b0  = (const float*)d_in[5];
    const float* W1  = (const float*)d_in[6];
    const float* a1s = (const float*)d_in[7];
    const float* a1d = (const float*)d_in[8];
    const float* b1  = (const float*)d_in[9];
    const float* W2  = (const float*)d_in[10];
    const float* a2s = (const float*)d_in[11];
    const float* a2d = (const float*)d_in[12];
    const float* b2  = (const float*)d_in[13];
    float* out = (float*)d_out;

    char* p = (char*)d_ws;
    auto take = [&](size_t bytes) -> void* {
        void* r = (void*)p;
        p += (bytes + 255) & ~(size_t)255;
        return r;
    };
    int*            ccnt     = (int*)take((size_t)NB * 4);
    int*            cbase    = (int*)take((size_t)(NB + 1) * 4);
    int*            ccur     = (int*)take((size_t)NB * 4);
    unsigned int*   cval     = (unsigned int*)take((size_t)ET * 4);
    int*            rowp     = (int*)take((size_t)(N_NODES + 1) * 4);
    unsigned short* csr_src  = (unsigned short*)take((size_t)ET * 2);
    float*          al       = (float*)take((size_t)N_NODES * 3 * 4);
    float*          ar       = (float*)take((size_t)N_NODES * 3 * 4);
    _Float16*       Hm16     = (_Float16*)take((size_t)N_NODES * 128 * 2);
    _Float16*       Omh      = (_Float16*)take((size_t)N_NODES * 128 * 2);
    float*          Hl       = (float*)take((size_t)N_NODES * 4);
    float*          Ol       = (float*)take((size_t)N_NODES * 4);
    _Float16*       Wt0      = (_Float16*)take((size_t)144 * 128 * 2);
    _Float16*       Wt1      = (_Float16*)take((size_t)144 * 128 * 2);
    float*          w128row1 = (float*)take((size_t)144 * 4);
    float*          H2       = (float*)take((size_t)N_NODES * OUTC * 4);
    float*          al2      = (float*)take((size_t)N_NODES * 4);
    float*          ar2      = (float*)take((size_t)N_NODES * 4);

    const int* esrc = ei;
    const int* edst = ei + N_EDGES;

    // CSR build (two-phase bin sort)
    hipMemsetAsync(ccnt, 0, (size_t)NB * 4, stream);
    const int cgrid = (ET + CT - 1) / CT;
    ccount_kernel<<<cgrid, 256, 0, stream>>>(edst, ccnt);
    cscan_kernel<<<1, 256, 0, stream>>>(ccnt, cbase, ccur);
    cscatter_kernel<<<cgrid, 256, 0, stream>>>(esrc, edst, ccur, cval);
    fine_kernel<<<NB, 512, 0, stream>>>(cval, cbase, rowp, csr_src);

    padw_kernel<<<(2 * 144 * 128 + 144 + 255) / 256, 256, 0, stream>>>(
        W0, a0s, a0d, W1, a1s, a1d, Wt0, Wt1, w128row1);

    const dim3 gemm_grid((N_NODES / 16 + 3) / 4, 3);
    const int  node_grid = (N_NODES + 3) / 4;

    // layer 0
    gemm_mfma_kernel<true, false><<<gemm_grid, 256, 0, stream>>>(
        x, (const _Float16*)nullptr, Ol, Wt0, w128row1, Hm16, Hl, al, ar);
    agg129_kernel<true, false><<<node_grid, 256, 0, stream>>>(
        Hm16, Hl, al, ar, rowp, csr_src, b0, Omh, Ol,
        nullptr, nullptr, nullptr, nullptr, nullptr, nullptr);

    // layer 1 (layer-2 node GEMM fused into epilogue)
    gemm_mfma_kernel<false, true><<<gemm_grid, 256, 0, stream>>>(
        (const float*)nullptr, Omh, Ol, Wt1, w128row1, Hm16, Hl, al, ar);
    agg129_kernel<true, true><<<node_grid, 256, 0, stream>>>(
        Hm16, Hl, al, ar, rowp, csr_src, b1, (_Float16*)nullptr, (float*)nullptr,
        W2, a2s, a2d, H2, al2, ar2);

    // layer 2 aggregate
    agg6_kernel<<<node_grid, 256, 0, stream>>>(H2, al2, ar2, rowp, csr_src, b2, out);
}

// Round 12
// 280.461 us; speedup vs baseline: 1.0701x; 1.0701x over previous
//
#include <hip/hip_runtime.h>

#define N_NODES 50000
#define N_EDGES 800000
#define ET (N_EDGES + N_NODES)   // edges + self loops = 850000
#define MID 129
#define OUTC 6
#define NB 196                   // coarse buckets: dst >> 8
#define CT 4096                  // edges per coarse-scatter block

typedef _Float16 half2v __attribute__((ext_vector_type(2)));
typedef _Float16 half8  __attribute__((ext_vector_type(8)));
typedef float    floatx4 __attribute__((ext_vector_type(4)));

__device__ __forceinline__ float lrelu(float x) { return fmaxf(x, 0.2f * x); }

// ---------------- CSR build: two-phase bin sort ----------------

__global__ void ccount_kernel(const int* __restrict__ dst, int* __restrict__ ccnt) {
    __shared__ int lh[NB];
    for (int i = threadIdx.x; i < NB; i += 256) lh[i] = 0;
    __syncthreads();
    int base = blockIdx.x * CT;
#pragma unroll 4
    for (int j = 0; j < CT; j += 256) {
        int e = base + j + threadIdx.x;
        if (e < ET) {
            int d = (e < N_EDGES) ? dst[e] : (e - N_EDGES);
            atomicAdd(&lh[d >> 8], 1);
        }
    }
    __syncthreads();
    for (int i = threadIdx.x; i < NB; i += 256) {
        int v = lh[i];
        if (v) atomicAdd(&ccnt[i], v);
    }
}

__global__ void cscan_kernel(const int* __restrict__ ccnt, int* __restrict__ cbase,
                             int* __restrict__ ccur) {
    __shared__ int buf[256];
    int t = threadIdx.x;
    buf[t] = (t < NB) ? ccnt[t] : 0;
    __syncthreads();
    for (int off = 1; off < 256; off <<= 1) {
        int v = (t >= off) ? buf[t - off] : 0;
        __syncthreads();
        buf[t] += v;
        __syncthreads();
    }
    int excl = t ? buf[t - 1] : 0;
    if (t < NB) { cbase[t] = excl; ccur[t] = excl; }
    if (t == NB - 1) cbase[NB] = buf[t];
}

__global__ void cscatter_kernel(const int* __restrict__ src, const int* __restrict__ dst,
                                int* __restrict__ ccur, unsigned int* __restrict__ cval) {
    __shared__ unsigned int staged[CT];
    __shared__ int lh[NB], lex[NB], lcur[NB], lgb[NB];
    __shared__ int sbuf[256];
    int tid = threadIdx.x;
    for (int i = tid; i < NB; i += 256) lh[i] = 0;
    __syncthreads();
    int base = blockIdx.x * CT;
    unsigned int myv[16];
    int myb[16];
    int myn = 0;
#pragma unroll
    for (int j = 0; j < 16; ++j) {
        int e = base + j * 256 + tid;
        if (e < ET) {
            int s, d;
            if (e < N_EDGES) { s = src[e]; d = dst[e]; }
            else             { s = d = e - N_EDGES; }
            int b = d >> 8;
            myv[j] = ((unsigned)b << 24) | ((unsigned)(d & 255) << 16) | (unsigned)s;
            myb[j] = b;
            atomicAdd(&lh[b], 1);
            myn = j + 1;
        }
    }
    __syncthreads();
    sbuf[tid] = (tid < NB) ? lh[tid] : 0;
    __syncthreads();
    for (int off = 1; off < 256; off <<= 1) {
        int v = (tid >= off) ? sbuf[tid - off] : 0;
        __syncthreads();
        sbuf[tid] += v;
        __syncthreads();
    }
    if (tid < NB) {
        int excl = tid ? sbuf[tid - 1] : 0;
        lex[tid] = excl;
        lcur[tid] = excl;
    }
    __syncthreads();
    for (int j = 0; j < myn; ++j) {
        int p = atomicAdd(&lcur[myb[j]], 1);
        staged[p] = myv[j];
    }
    __syncthreads();
    if (tid < NB) {
        int c = lh[tid];
        lgb[tid] = c ? atomicAdd(&ccur[tid], c) : 0;
    }
    __syncthreads();
    int tot = ET - base; if (tot > CT) tot = CT;
    for (int i = tid; i < tot; i += 256) {
        unsigned int v = staged[i];
        int b = v >> 24;
        cval[lgb[b] + (i - lex[b])] = v;
    }
}

__global__ __launch_bounds__(512)
void fine_kernel(const unsigned int* __restrict__ cval, const int* __restrict__ cbase,
                 int* __restrict__ rowp, unsigned short* __restrict__ csr_src) {
    __shared__ int h[256], cur[256], sb[256];
    int b = blockIdx.x;
    int beg = cbase[b], end = cbase[b + 1];
    int t = threadIdx.x;
    if (t < 256) h[t] = 0;
    __syncthreads();
    for (int i = beg + t; i < end; i += 512)
        atomicAdd(&h[(cval[i] >> 16) & 255], 1);
    __syncthreads();
    if (t < 256) sb[t] = h[t];
    __syncthreads();
    for (int off = 1; off < 256; off <<= 1) {
        int v = 0;
        if (t < 256 && t >= off) v = sb[t - off];
        __syncthreads();
        if (t < 256) sb[t] += v;
        __syncthreads();
    }
    if (t < 256) {
        int excl = t ? sb[t - 1] : 0;
        cur[t] = excl;
        int dstv = (b << 8) + t;
        if (dstv <= N_NODES) rowp[dstv] = beg + excl;
    }
    __syncthreads();
    for (int i = beg + t; i < end; i += 512) {
        unsigned int v = cval[i];
        int low = (v >> 16) & 255;
        int p = atomicAdd(&cur[low], 1);
        csr_src[beg + p] = (unsigned short)(v & 0xFFFFu);
    }
}

// ---- Build MFMA weight blocks: Wt[l][144][128] fp16 (n-major, k-minor) ----
__global__ void padw_kernel(const float* __restrict__ W0, const float* __restrict__ a0s,
                            const float* __restrict__ a0d, const float* __restrict__ W1,
                            const float* __restrict__ a1s, const float* __restrict__ a1d,
                            _Float16* __restrict__ Wt0, _Float16* __restrict__ Wt1,
                            float* __restrict__ w128row1) {
    const int SEG = 144 * 128;
    int i = blockIdx.x * blockDim.x + threadIdx.x;
    if (i < 2 * SEG) {
        int l = i / SEG;
        int ii = i - l * SEG;
        int n = ii >> 7, k = ii & 127;
        const float* W = l ? W1 : W0;
        const float* as = l ? a1s : a0s;
        const float* ad = l ? a1d : a0d;
        float v = 0.f;
        if (n < 129) v = W[k * MID + n];
        else if (n < 132) {
            int h = n - 129;
            float sum = 0.f;
            for (int c = 0; c < 43; ++c) sum += W[k * MID + 43 * h + c] * as[43 * h + c];
            v = sum;
        } else if (n < 135) {
            int h = n - 132;
            float sum = 0.f;
            for (int c = 0; c < 43; ++c) sum += W[k * MID + 43 * h + c] * ad[43 * h + c];
            v = sum;
        }
        (l ? Wt1 : Wt0)[ii] = (_Float16)v;
    } else if (i < 2 * SEG + 144) {
        int n = i - 2 * SEG;
        float v = 0.f;
        if (n < 129) v = W1[128 * MID + n];
        else if (n < 132) {
            int h = n - 129;
            float sum = 0.f;
            for (int c = 0; c < 43; ++c) sum += W1[128 * MID + 43 * h + c] * a1s[43 * h + c];
            v = sum;
        } else if (n < 135) {
            int h = n - 132;
            float sum = 0.f;
            for (int c = 0; c < 43; ++c) sum += W1[128 * MID + 43 * h + c] * a1d[43 * h + c];
            v = sum;
        }
        w128row1[n] = v;
    }
}

// ---------------- MFMA GEMM + fused logits (al/ar stored stride-4) ----------------
template <bool SRC32, bool RANK1>
__global__ __launch_bounds__(256)
void gemm_mfma_kernel(const float* __restrict__ X32, const _Float16* __restrict__ Xh,
                      const float* __restrict__ Xl,
                      const _Float16* __restrict__ Wt, const float* __restrict__ w128,
                      _Float16* __restrict__ Hm16, float* __restrict__ Hl,
                      float* __restrict__ al4, float* __restrict__ ar4) {
    int wave = threadIdx.x >> 6, lane = threadIdx.x & 63;
    int mt = blockIdx.x * 4 + wave;
    if (mt * 16 >= N_NODES) return;
    int t = lane & 15, quad = lane >> 4;
    int row0 = mt * 16;

    half8 af[4];
    if (SRC32) {
        const float* arow = X32 + ((size_t)(row0 + t) << 7) + quad * 8;
#pragma unroll
        for (int kt = 0; kt < 4; ++kt) {
            float4 a0 = *(const float4*)(arow + kt * 32);
            float4 a1 = *(const float4*)(arow + kt * 32 + 4);
            half8 h;
            h[0] = (_Float16)a0.x; h[1] = (_Float16)a0.y;
            h[2] = (_Float16)a0.z; h[3] = (_Float16)a0.w;
            h[4] = (_Float16)a1.x; h[5] = (_Float16)a1.y;
            h[6] = (_Float16)a1.z; h[7] = (_Float16)a1.w;
            af[kt] = h;
        }
    } else {
        const _Float16* arow = Xh + ((size_t)(row0 + t) << 7) + quad * 8;
#pragma unroll
        for (int kt = 0; kt < 4; ++kt) af[kt] = *(const half8*)(arow + kt * 32);
    }

    floatx4 acc[3];
#pragma unroll
    for (int nt = 0; nt < 3; ++nt) {
        int ntile = blockIdx.y * 3 + nt;
        const _Float16* brow = Wt + ((size_t)(ntile * 16 + t) << 7) + quad * 8;
        floatx4 a = {0.f, 0.f, 0.f, 0.f};
#pragma unroll
        for (int kt = 0; kt < 4; ++kt) {
            half8 b = *(const half8*)(brow + kt * 32);
            a = __builtin_amdgcn_mfma_f32_16x16x32_f16(af[kt], b, a, 0, 0, 0);
        }
        acc[nt] = a;
    }

#pragma unroll
    for (int r = 0; r < 4; ++r) {
        int row = row0 + quad * 4 + r;
        float xl = RANK1 ? Xl[row] : 0.f;
#pragma unroll
        for (int nt = 0; nt < 3; ++nt) {
            int n = (blockIdx.y * 3 + nt) * 16 + t;
            float v = acc[nt][r];
            if (RANK1) v += xl * w128[n];
            if (n < 128) {
                Hm16[((size_t)row << 7) + n] = (_Float16)v;
            } else if (n == 128) {
                Hl[row] = v;
            } else if (n < 132) {
                al4[row * 4 + (n - 129)] = v;
            } else if (n < 135) {
                ar4[row * 4 + (n - 132)] = v;
            }
        }
    }
}

// ------- fused softmax + aggregation (129 ch, 3 heads) -------
// 16 lanes per node, 4 nodes per wave, 16 nodes per block.
// Per-quad serial edge loop: no accv cross-lane reduction; s-sums reduce in-quad.
// LDS: [wave][quad][17 float4] — 272B quad stride -> disjoint bank groups.
template <bool ACT, bool L2EPI>
__global__ void agg129_kernel(const _Float16* __restrict__ Hm16, const float* __restrict__ Hl,
                              const float* __restrict__ al4, const float* __restrict__ ar4,
                              const int* __restrict__ rowp, const unsigned short* __restrict__ srcs,
                              const float* __restrict__ bias, _Float16* __restrict__ Omh,
                              float* __restrict__ Ol,
                              const float* __restrict__ W2, const float* __restrict__ a2s,
                              const float* __restrict__ a2d, float* __restrict__ H2,
                              float* __restrict__ al2, float* __restrict__ ar2) {
    __shared__ float4 exs[4][4][17];
    int lane = threadIdx.x & 63;
    int wv   = threadIdx.x >> 6;
    int qd   = lane >> 4;      // node slot within wave
    int q    = lane & 15;      // lane within quad; channel group cb = 8q
    int wid  = ((blockIdx.x * 4 + wv) << 2) + qd;
    bool active = wid < N_NODES;
    int widc = active ? wid : 0;

    int beg = 0, end = 0;
    if (active) { beg = rowp[wid]; end = rowp[wid + 1]; }
    float4 arv = *(const float4*)(ar4 + (size_t)widc * 4);
    float ard0 = arv.x, ard1 = arv.y, ard2 = arv.z;

    int cb = 8 * q;
    bool bm0[8], bm1[8];
#pragma unroll
    for (int j = 0; j < 8; ++j) {
        bm0[j] = (cb + j) < 43;
        bm1[j] = (cb + j) < 86;
    }
    // v_perm selectors (HW-verified R9/R11): bytes 4..7 = arg0 (e0|e1), 0..3 = arg1 (e2|-)
    unsigned selv[4];
#pragma unroll
    for (int p = 0; p < 4; ++p) {
        int c0 = cb + 2 * p, c1 = c0 + 1;
        int l0 = (c0 < 43) ? 4 : (c0 < 86) ? 6 : 0;
        int l1 = (c1 < 43) ? 4 : (c1 < 86) ? 6 : 0;
        selv[p] = (unsigned)l0 | ((unsigned)(l0 + 1) << 8) |
                  ((unsigned)l1 << 16) | ((unsigned)(l1 + 1) << 24);
    }

    float accv[8];
#pragma unroll
    for (int j = 0; j < 8; ++j) accv[j] = 0.f;
    float acc128 = 0.f;
    float s0 = 0.f, s1 = 0.f, s2 = 0.f;
    float4* exq = exs[wv][qd];

    for (int base = beg; base < end; base += 16) {
        int i = base + q;
        float e0 = 0.f, e1 = 0.f, e2 = 0.f;
        int s = 0;
        if (i < end) {
            s = (int)srcs[i];
            float4 av = *(const float4*)(al4 + (size_t)s * 4);
            e0 = __expf(lrelu(av.x + ard0));
            e1 = __expf(lrelu(av.y + ard1));
            e2 = __expf(lrelu(av.z + ard2));
            s0 += e0; s1 += e1; s2 += e2;
        }
        exq[q] = make_float4(e0, e1, e2, __int_as_float(s));
        int cnt = end - base; if (cnt > 16) cnt = 16;
        for (int t = 0; t < cnt; ++t) {
            float4 ed = exq[t];                  // quad-uniform broadcast
            int ss = __float_as_int(ed.w);
            half8 hv = *(const half8*)(Hm16 + ((size_t)ss << 7) + cb);
            unsigned p01 = __builtin_bit_cast(unsigned, __builtin_amdgcn_cvt_pkrtz(ed.x, ed.y));
            unsigned p2z = __builtin_bit_cast(unsigned, __builtin_amdgcn_cvt_pkrtz(ed.z, ed.z));
            if (q == 0) acc128 += ed.z * Hl[ss];
#pragma unroll
            for (int p = 0; p < 4; ++p) {
                unsigned wp = __builtin_amdgcn_perm(p01, p2z, selv[p]);
                half2v w2 = __builtin_bit_cast(half2v, wp);
                accv[2 * p]     += (float)w2[0] * (float)hv[2 * p];
                accv[2 * p + 1] += (float)w2[1] * (float)hv[2 * p + 1];
            }
        }
    }
    // in-quad reductions for denominators (accv needs none: quad owns its node serially)
#pragma unroll
    for (int off = 1; off < 16; off <<= 1) {
        s0 += __shfl_xor(s0, off, 64);
        s1 += __shfl_xor(s1, off, 64);
        s2 += __shfl_xor(s2, off, 64);
    }
    float d0 = 1.f / (s0 + 1e-16f);
    float d1 = 1.f / (s1 + 1e-16f);
    float d2 = 1.f / (s2 + 1e-16f);

    float4 bv0 = *(const float4*)(bias + cb);
    float4 bv1 = *(const float4*)(bias + cb + 4);
    float bb[8] = {bv0.x, bv0.y, bv0.z, bv0.w, bv1.x, bv1.y, bv1.z, bv1.w};
    float o[8];
#pragma unroll
    for (int j = 0; j < 8; ++j) {
        float dv = bm0[j] ? d0 : (bm1[j] ? d1 : d2);
        o[j] = accv[j] * dv + bb[j];
        if (ACT) o[j] = lrelu(o[j]);
    }
    float o128 = 0.f;
    if (q == 0) {
        o128 = acc128 * d2 + bias[128];
        if (ACT) o128 = lrelu(o128);
    }
    if (!L2EPI) {
        if (active) {
            half8 oh;
#pragma unroll
            for (int j = 0; j < 8; ++j) oh[j] = (_Float16)o[j];
            *(half8*)(Omh + ((size_t)wid << 7) + cb) = oh;
            if (q == 0) Ol[wid] = o128;
        }
    } else {
        float pr[OUTC];
#pragma unroll
        for (int c = 0; c < OUTC; ++c) pr[c] = 0.f;
#pragma unroll
        for (int j = 0; j < 8; ++j) {
            const float* wr = W2 + (cb + j) * OUTC;
            float ov = o[j];
#pragma unroll
            for (int c = 0; c < OUTC; ++c) pr[c] += ov * wr[c];
        }
        if (q == 0) {
#pragma unroll
            for (int c = 0; c < OUTC; ++c) pr[c] += o128 * W2[128 * OUTC + c];
        }
#pragma unroll
        for (int off = 1; off < 16; off <<= 1)
#pragma unroll
            for (int c = 0; c < OUTC; ++c) pr[c] += __shfl_xor(pr[c], off, 64);
        if (active && q == 0) {
            float sl = 0.f, sr = 0.f;
#pragma unroll
            for (int c = 0; c < OUTC; ++c) {
                H2[wid * OUTC + c] = pr[c];
                sl += pr[c] * a2s[c];
                sr += pr[c] * a2d[c];
            }
            al2[wid] = sl;
            ar2[wid] = sr;
        }
    }
}

// ---------------- layer 2 aggregate: 8 lanes per node, 8 nodes per wave ----------------
__global__ void agg6_kernel(const float* __restrict__ H2, const float* __restrict__ al2,
                            const float* __restrict__ ar2, const int* __restrict__ rowp,
                            const unsigned short* __restrict__ srcs, const float* __restrict__ b2,
                            float* __restrict__ out) {
    __shared__ float2 exs[4][8][9];   // 72B group stride -> disjoint bank pairs
    int lane = threadIdx.x & 63;
    int wv   = threadIdx.x >> 6;
    int g8   = lane >> 3;      // node slot within wave
    int c    = lane & 7;       // lane within group (channels 0..5 used)
    int wid  = ((blockIdx.x * 4 + wv) << 3) + g8;
    bool active = wid < N_NODES;
    int widc = active ? wid : 0;
    int beg = 0, end = 0;
    if (active) { beg = rowp[wid]; end = rowp[wid + 1]; }
    float ard = ar2[widc];
    int cc = (c < OUTC) ? c : 0;
    float ssum = 0.f, acc = 0.f;
    float2* exq = exs[wv][g8];
    for (int base = beg; base < end; base += 8) {
        int i = base + c;
        float ex = 0.f;
        int s = 0;
        if (i < end) {
            s = (int)srcs[i];
            ex = __expf(lrelu(al2[s] + ard));
            ssum += ex;
        }
        exq[c] = make_float2(ex, __int_as_float(s));
        int cnt = end - base; if (cnt > 8) cnt = 8;
        for (int t = 0; t < cnt; ++t) {
            float2 ed = exq[t];
            int ss = __float_as_int(ed.y);
            acc += ed.x * H2[ss * OUTC + cc];
        }
    }
#pragma unroll
    for (int off = 1; off < 8; off <<= 1) ssum += __shfl_xor(ssum, off, 64);
    float dinv = 1.f / (ssum + 1e-16f);
    if (active && c < OUTC) out[(size_t)wid * OUTC + c] = acc * dinv + b2[c];
}

// ---------------- launch ----------------

extern "C" void kernel_launch(void* const* d_in, const int* in_sizes, int n_in,
                              void* d_out, int out_size, void* d_ws, size_t ws_size,
                              hipStream_t stream) {
    const float* x   = (const float*)d_in[0];
    const int*   ei  = (const int*)d_in[1];
    const float* W0  = (const float*)d_in[2];
    const float* a0s = (const float*)d_in[3];
    const float* a0d = (const float*)d_in[4];
    const float* b0  = (const float*)d_in[5];
    const float* W1  = (const float*)d_in[6];
    const float* a1s = (const float*)d_in[7];
    const float* a1d = (const float*)d_in[8];
    const float* b1  = (const float*)d_in[9];
    const float* W2  = (const float*)d_in[10];
    const float* a2s = (const float*)d_in[11];
    const float* a2d = (const float*)d_in[12];
    const float* b2  = (const float*)d_in[13];
    float* out = (float*)d_out;

    char* p = (char*)d_ws;
    auto take = [&](size_t bytes) -> void* {
        void* r = (void*)p;
        p += (bytes + 255) & ~(size_t)255;
        return r;
    };
    int*            ccnt     = (int*)take((size_t)NB * 4);
    int*            cbase    = (int*)take((size_t)(NB + 1) * 4);
    int*            ccur     = (int*)take((size_t)NB * 4);
    unsigned int*   cval     = (unsigned int*)take((size_t)ET * 4);
    int*            rowp     = (int*)take((size_t)(N_NODES + 1) * 4);
    unsigned short* csr_src  = (unsigned short*)take((size_t)ET * 2);
    float*          al4      = (float*)take((size_t)N_NODES * 4 * 4);
    float*          ar4      = (float*)take((size_t)N_NODES * 4 * 4);
    _Float16*       Hm16     = (_Float16*)take((size_t)N_NODES * 128 * 2);
    _Float16*       Omh      = (_Float16*)take((size_t)N_NODES * 128 * 2);
    float*          Hl       = (float*)take((size_t)N_NODES * 4);
    float*          Ol       = (float*)take((size_t)N_NODES * 4);
    _Float16*       Wt0      = (_Float16*)take((size_t)144 * 128 * 2);
    _Float16*       Wt1      = (_Float16*)take((size_t)144 * 128 * 2);
    float*          w128row1 = (float*)take((size_t)144 * 4);
    float*          H2       = (float*)take((size_t)N_NODES * OUTC * 4);
    float*          al2      = (float*)take((size_t)N_NODES * 4);
    float*          ar2      = (float*)take((size_t)N_NODES * 4);

    const int* esrc = ei;
    const int* edst = ei + N_EDGES;

    // CSR build (two-phase bin sort)
    hipMemsetAsync(ccnt, 0, (size_t)NB * 4, stream);
    const int cgrid = (ET + CT - 1) / CT;
    ccount_kernel<<<cgrid, 256, 0, stream>>>(edst, ccnt);
    cscan_kernel<<<1, 256, 0, stream>>>(ccnt, cbase, ccur);
    cscatter_kernel<<<cgrid, 256, 0, stream>>>(esrc, edst, ccur, cval);
    fine_kernel<<<NB, 512, 0, stream>>>(cval, cbase, rowp, csr_src);

    padw_kernel<<<(2 * 144 * 128 + 144 + 255) / 256, 256, 0, stream>>>(
        W0, a0s, a0d, W1, a1s, a1d, Wt0, Wt1, w128row1);

    const dim3 gemm_grid((N_NODES / 16 + 3) / 4, 3);
    const int  agg129_grid = (N_NODES + 15) / 16;
    const int  agg6_grid   = (N_NODES + 31) / 32;

    // layer 0
    gemm_mfma_kernel<true, false><<<gemm_grid, 256, 0, stream>>>(
        x, (const _Float16*)nullptr, Ol, Wt0, w128row1, Hm16, Hl, al4, ar4);
    agg129_kernel<true, false><<<agg129_grid, 256, 0, stream>>>(
        Hm16, Hl, al4, ar4, rowp, csr_src, b0, Omh, Ol,
        nullptr, nullptr, nullptr, nullptr, nullptr, nullptr);

    // layer 1 (layer-2 node GEMM fused into epilogue)
    gemm_mfma_kernel<false, true><<<gemm_grid, 256, 0, stream>>>(
        (const float*)nullptr, Omh, Ol, Wt1, w128row1, Hm16, Hl, al4, ar4);
    agg129_kernel<true, true><<<agg129_grid, 256, 0, stream>>>(
        Hm16, Hl, al4, ar4, rowp, csr_src, b1, (_Float16*)nullptr, (float*)nullptr,
        W2, a2s, a2d, H2, al2, ar2);

    // layer 2 aggregate
    agg6_kernel<<<agg6_grid, 256, 0, stream>>>(H2, al2, ar2, rowp, csr_src, b2, out);
}

// Round 13
// 273.763 us; speedup vs baseline: 1.0963x; 1.0245x over previous
//
#include <hip/hip_runtime.h>

#define N_NODES 50000
#define N_EDGES 800000
#define ET (N_EDGES + N_NODES)   // edges + self loops = 850000
#define MID 129
#define OUTC 6
#define NB 196                   // coarse buckets: dst >> 8
#define CT 4096                  // edges per coarse-scatter block

typedef _Float16 half2v __attribute__((ext_vector_type(2)));
typedef _Float16 half8  __attribute__((ext_vector_type(8)));
typedef float    floatx4 __attribute__((ext_vector_type(4)));

__device__ __forceinline__ float lrelu(float x) { return fmaxf(x, 0.2f * x); }

// ---------------- CSR build: two-phase bin sort ----------------

__global__ void ccount_kernel(const int* __restrict__ dst, int* __restrict__ ccnt) {
    __shared__ int lh[NB];
    for (int i = threadIdx.x; i < NB; i += 256) lh[i] = 0;
    __syncthreads();
    int base = blockIdx.x * CT;
#pragma unroll 4
    for (int j = 0; j < CT; j += 256) {
        int e = base + j + threadIdx.x;
        if (e < ET) {
            int d = (e < N_EDGES) ? dst[e] : (e - N_EDGES);
            atomicAdd(&lh[d >> 8], 1);
        }
    }
    __syncthreads();
    for (int i = threadIdx.x; i < NB; i += 256) {
        int v = lh[i];
        if (v) atomicAdd(&ccnt[i], v);
    }
}

__global__ void cscan_kernel(const int* __restrict__ ccnt, int* __restrict__ cbase,
                             int* __restrict__ ccur) {
    __shared__ int buf[256];
    int t = threadIdx.x;
    buf[t] = (t < NB) ? ccnt[t] : 0;
    __syncthreads();
    for (int off = 1; off < 256; off <<= 1) {
        int v = (t >= off) ? buf[t - off] : 0;
        __syncthreads();
        buf[t] += v;
        __syncthreads();
    }
    int excl = t ? buf[t - 1] : 0;
    if (t < NB) { cbase[t] = excl; ccur[t] = excl; }
    if (t == NB - 1) cbase[NB] = buf[t];
}

__global__ void cscatter_kernel(const int* __restrict__ src, const int* __restrict__ dst,
                                int* __restrict__ ccur, unsigned int* __restrict__ cval) {
    __shared__ unsigned int staged[CT];
    __shared__ int lh[NB], lex[NB], lcur[NB], lgb[NB];
    __shared__ int sbuf[256];
    int tid = threadIdx.x;
    for (int i = tid; i < NB; i += 256) lh[i] = 0;
    __syncthreads();
    int base = blockIdx.x * CT;
    unsigned int myv[16];
    int myb[16];
    int myn = 0;
#pragma unroll
    for (int j = 0; j < 16; ++j) {
        int e = base + j * 256 + tid;
        if (e < ET) {
            int s, d;
            if (e < N_EDGES) { s = src[e]; d = dst[e]; }
            else             { s = d = e - N_EDGES; }
            int b = d >> 8;
            myv[j] = ((unsigned)b << 24) | ((unsigned)(d & 255) << 16) | (unsigned)s;
            myb[j] = b;
            atomicAdd(&lh[b], 1);
            myn = j + 1;
        }
    }
    __syncthreads();
    sbuf[tid] = (tid < NB) ? lh[tid] : 0;
    __syncthreads();
    for (int off = 1; off < 256; off <<= 1) {
        int v = (tid >= off) ? sbuf[tid - off] : 0;
        __syncthreads();
        sbuf[tid] += v;
        __syncthreads();
    }
    if (tid < NB) {
        int excl = tid ? sbuf[tid - 1] : 0;
        lex[tid] = excl;
        lcur[tid] = excl;
    }
    __syncthreads();
    for (int j = 0; j < myn; ++j) {
        int p = atomicAdd(&lcur[myb[j]], 1);
        staged[p] = myv[j];
    }
    __syncthreads();
    if (tid < NB) {
        int c = lh[tid];
        lgb[tid] = c ? atomicAdd(&ccur[tid], c) : 0;
    }
    __syncthreads();
    int tot = ET - base; if (tot > CT) tot = CT;
    for (int i = tid; i < tot; i += 256) {
        unsigned int v = staged[i];
        int b = v >> 24;
        cval[lgb[b] + (i - lex[b])] = v;
    }
}

__global__ __launch_bounds__(512)
void fine_kernel(const unsigned int* __restrict__ cval, const int* __restrict__ cbase,
                 int* __restrict__ rowp, unsigned short* __restrict__ csr_src) {
    __shared__ int h[256], cur[256], sb[256];
    int b = blockIdx.x;
    int beg = cbase[b], end = cbase[b + 1];
    int t = threadIdx.x;
    if (t < 256) h[t] = 0;
    __syncthreads();
    for (int i = beg + t; i < end; i += 512)
        atomicAdd(&h[(cval[i] >> 16) & 255], 1);
    __syncthreads();
    if (t < 256) sb[t] = h[t];
    __syncthreads();
    for (int off = 1; off < 256; off <<= 1) {
        int v = 0;
        if (t < 256 && t >= off) v = sb[t - off];
        __syncthreads();
        if (t < 256) sb[t] += v;
        __syncthreads();
    }
    if (t < 256) {
        int excl = t ? sb[t - 1] : 0;
        cur[t] = excl;
        int dstv = (b << 8) + t;
        if (dstv <= N_NODES) rowp[dstv] = beg + excl;
    }
    __syncthreads();
    for (int i = beg + t; i < end; i += 512) {
        unsigned int v = cval[i];
        int low = (v >> 16) & 255;
        int p = atomicAdd(&cur[low], 1);
        csr_src[beg + p] = (unsigned short)(v & 0xFFFFu);
    }
}

// ---- Build MFMA weight blocks: Wt[l][144][128] fp16 (n-major, k-minor) ----
__global__ void padw_kernel(const float* __restrict__ W0, const float* __restrict__ a0s,
                            const float* __restrict__ a0d, const float* __restrict__ W1,
                            const float* __restrict__ a1s, const float* __restrict__ a1d,
                            _Float16* __restrict__ Wt0, _Float16* __restrict__ Wt1,
                            float* __restrict__ w128row1) {
    const int SEG = 144 * 128;
    int i = blockIdx.x * blockDim.x + threadIdx.x;
    if (i < 2 * SEG) {
        int l = i / SEG;
        int ii = i - l * SEG;
        int n = ii >> 7, k = ii & 127;
        const float* W = l ? W1 : W0;
        const float* as = l ? a1s : a0s;
        const float* ad = l ? a1d : a0d;
        float v = 0.f;
        if (n < 129) v = W[k * MID + n];
        else if (n < 132) {
            int h = n - 129;
            float sum = 0.f;
            for (int c = 0; c < 43; ++c) sum += W[k * MID + 43 * h + c] * as[43 * h + c];
            v = sum;
        } else if (n < 135) {
            int h = n - 132;
            float sum = 0.f;
            for (int c = 0; c < 43; ++c) sum += W[k * MID + 43 * h + c] * ad[43 * h + c];
            v = sum;
        }
        (l ? Wt1 : Wt0)[ii] = (_Float16)v;
    } else if (i < 2 * SEG + 144) {
        int n = i - 2 * SEG;
        float v = 0.f;
        if (n < 129) v = W1[128 * MID + n];
        else if (n < 132) {
            int h = n - 129;
            float sum = 0.f;
            for (int c = 0; c < 43; ++c) sum += W1[128 * MID + 43 * h + c] * a1s[43 * h + c];
            v = sum;
        } else if (n < 135) {
            int h = n - 132;
            float sum = 0.f;
            for (int c = 0; c < 43; ++c) sum += W1[128 * MID + 43 * h + c] * a1d[43 * h + c];
            v = sum;
        }
        w128row1[n] = v;
    }
}

// ---------------- MFMA GEMM + fused logits (al/ar stored stride-4) ----------------
template <bool SRC32, bool RANK1>
__global__ __launch_bounds__(256)
void gemm_mfma_kernel(const float* __restrict__ X32, const _Float16* __restrict__ Xh,
                      const float* __restrict__ Xl,
                      const _Float16* __restrict__ Wt, const float* __restrict__ w128,
                      _Float16* __restrict__ Hm16, float* __restrict__ Hl,
                      float* __restrict__ al4, float* __restrict__ ar4) {
    int wave = threadIdx.x >> 6, lane = threadIdx.x & 63;
    int mt = blockIdx.x * 4 + wave;
    if (mt * 16 >= N_NODES) return;
    int t = lane & 15, quad = lane >> 4;
    int row0 = mt * 16;

    half8 af[4];
    if (SRC32) {
        const float* arow = X32 + ((size_t)(row0 + t) << 7) + quad * 8;
#pragma unroll
        for (int kt = 0; kt < 4; ++kt) {
            float4 a0 = *(const float4*)(arow + kt * 32);
            float4 a1 = *(const float4*)(arow + kt * 32 + 4);
            half8 h;
            h[0] = (_Float16)a0.x; h[1] = (_Float16)a0.y;
            h[2] = (_Float16)a0.z; h[3] = (_Float16)a0.w;
            h[4] = (_Float16)a1.x; h[5] = (_Float16)a1.y;
            h[6] = (_Float16)a1.z; h[7] = (_Float16)a1.w;
            af[kt] = h;
        }
    } else {
        const _Float16* arow = Xh + ((size_t)(row0 + t) << 7) + quad * 8;
#pragma unroll
        for (int kt = 0; kt < 4; ++kt) af[kt] = *(const half8*)(arow + kt * 32);
    }

    floatx4 acc[3];
#pragma unroll
    for (int nt = 0; nt < 3; ++nt) {
        int ntile = blockIdx.y * 3 + nt;
        const _Float16* brow = Wt + ((size_t)(ntile * 16 + t) << 7) + quad * 8;
        floatx4 a = {0.f, 0.f, 0.f, 0.f};
#pragma unroll
        for (int kt = 0; kt < 4; ++kt) {
            half8 b = *(const half8*)(brow + kt * 32);
            a = __builtin_amdgcn_mfma_f32_16x16x32_f16(af[kt], b, a, 0, 0, 0);
        }
        acc[nt] = a;
    }

#pragma unroll
    for (int r = 0; r < 4; ++r) {
        int row = row0 + quad * 4 + r;
        float xl = RANK1 ? Xl[row] : 0.f;
#pragma unroll
        for (int nt = 0; nt < 3; ++nt) {
            int n = (blockIdx.y * 3 + nt) * 16 + t;
            float v = acc[nt][r];
            if (RANK1) v += xl * w128[n];
            if (n < 128) {
                Hm16[((size_t)row << 7) + n] = (_Float16)v;
            } else if (n == 128) {
                Hl[row] = v;
            } else if (n < 132) {
                al4[row * 4 + (n - 129)] = v;
            } else if (n < 135) {
                ar4[row * 4 + (n - 132)] = v;
            }
        }
    }
}

// ------- fused softmax + aggregation (129 ch, 3 heads) -------
// 16 lanes per node, 4 nodes per wave; consume loop unrolled x2 (2 gathers in flight/quad).
template <bool ACT, bool L2EPI>
__global__ void agg129_kernel(const _Float16* __restrict__ Hm16, const float* __restrict__ Hl,
                              const float* __restrict__ al4, const float* __restrict__ ar4,
                              const int* __restrict__ rowp, const unsigned short* __restrict__ srcs,
                              const float* __restrict__ bias, _Float16* __restrict__ Omh,
                              float* __restrict__ Ol,
                              const float* __restrict__ W2, const float* __restrict__ a2s,
                              const float* __restrict__ a2d, float* __restrict__ H2,
                              float* __restrict__ al2, float* __restrict__ ar2) {
    __shared__ float4 exs[4][4][17];
    int lane = threadIdx.x & 63;
    int wv   = threadIdx.x >> 6;
    int qd   = lane >> 4;      // node slot within wave
    int q    = lane & 15;      // lane within quad; channel group cb = 8q
    int wid  = ((blockIdx.x * 4 + wv) << 2) + qd;
    bool active = wid < N_NODES;
    int widc = active ? wid : 0;

    int beg = 0, end = 0;
    if (active) { beg = rowp[wid]; end = rowp[wid + 1]; }
    float4 arv = *(const float4*)(ar4 + (size_t)widc * 4);
    float ard0 = arv.x, ard1 = arv.y, ard2 = arv.z;

    int cb = 8 * q;
    bool bm0[8], bm1[8];
#pragma unroll
    for (int j = 0; j < 8; ++j) {
        bm0[j] = (cb + j) < 43;
        bm1[j] = (cb + j) < 86;
    }
    // v_perm selectors (HW-verified R9/R11): bytes 4..7 = arg0 (e0|e1), 0..3 = arg1 (e2|-)
    unsigned selv[4];
#pragma unroll
    for (int p = 0; p < 4; ++p) {
        int c0 = cb + 2 * p, c1 = c0 + 1;
        int l0 = (c0 < 43) ? 4 : (c0 < 86) ? 6 : 0;
        int l1 = (c1 < 43) ? 4 : (c1 < 86) ? 6 : 0;
        selv[p] = (unsigned)l0 | ((unsigned)(l0 + 1) << 8) |
                  ((unsigned)l1 << 16) | ((unsigned)(l1 + 1) << 24);
    }

    float accv[8];
#pragma unroll
    for (int j = 0; j < 8; ++j) accv[j] = 0.f;
    float acc128 = 0.f;
    float s0 = 0.f, s1 = 0.f, s2 = 0.f;
    float4* exq = exs[wv][qd];

    for (int base = beg; base < end; base += 16) {
        int i = base + q;
        float e0 = 0.f, e1 = 0.f, e2 = 0.f;
        int s = 0;
        if (i < end) {
            s = (int)srcs[i];
            float4 av = *(const float4*)(al4 + (size_t)s * 4);
            e0 = __expf(lrelu(av.x + ard0));
            e1 = __expf(lrelu(av.y + ard1));
            e2 = __expf(lrelu(av.z + ard2));
            s0 += e0; s1 += e1; s2 += e2;
        }
        exq[q] = make_float4(e0, e1, e2, __int_as_float(s));
        int cnt = end - base; if (cnt > 16) cnt = 16;
        int t = 0;
        for (; t + 1 < cnt; t += 2) {
            float4 eda = exq[t];
            float4 edb = exq[t + 1];
            int sa = __float_as_int(eda.w);
            int sb = __float_as_int(edb.w);
            half8 hva = *(const half8*)(Hm16 + ((size_t)sa << 7) + cb);
            half8 hvb = *(const half8*)(Hm16 + ((size_t)sb << 7) + cb);
            if (q == 0) {
                float hla = Hl[sa];
                float hlb = Hl[sb];
                acc128 += eda.z * hla + edb.z * hlb;
            }
            unsigned pa01 = __builtin_bit_cast(unsigned, __builtin_amdgcn_cvt_pkrtz(eda.x, eda.y));
            unsigned pa2z = __builtin_bit_cast(unsigned, __builtin_amdgcn_cvt_pkrtz(eda.z, eda.z));
            unsigned pb01 = __builtin_bit_cast(unsigned, __builtin_amdgcn_cvt_pkrtz(edb.x, edb.y));
            unsigned pb2z = __builtin_bit_cast(unsigned, __builtin_amdgcn_cvt_pkrtz(edb.z, edb.z));
#pragma unroll
            for (int p = 0; p < 4; ++p) {
                unsigned wpa = __builtin_amdgcn_perm(pa01, pa2z, selv[p]);
                unsigned wpb = __builtin_amdgcn_perm(pb01, pb2z, selv[p]);
                half2v w2a = __builtin_bit_cast(half2v, wpa);
                half2v w2b = __builtin_bit_cast(half2v, wpb);
                accv[2 * p]     += (float)w2a[0] * (float)hva[2 * p];
                accv[2 * p + 1] += (float)w2a[1] * (float)hva[2 * p + 1];
                accv[2 * p]     += (float)w2b[0] * (float)hvb[2 * p];
                accv[2 * p + 1] += (float)w2b[1] * (float)hvb[2 * p + 1];
            }
        }
        if (t < cnt) {
            float4 ed = exq[t];
            int ss = __float_as_int(ed.w);
            half8 hv = *(const half8*)(Hm16 + ((size_t)ss << 7) + cb);
            if (q == 0) acc128 += ed.z * Hl[ss];
            unsigned p01 = __builtin_bit_cast(unsigned, __builtin_amdgcn_cvt_pkrtz(ed.x, ed.y));
            unsigned p2z = __builtin_bit_cast(unsigned, __builtin_amdgcn_cvt_pkrtz(ed.z, ed.z));
#pragma unroll
            for (int p = 0; p < 4; ++p) {
                unsigned wp = __builtin_amdgcn_perm(p01, p2z, selv[p]);
                half2v w2 = __builtin_bit_cast(half2v, wp);
                accv[2 * p]     += (float)w2[0] * (float)hv[2 * p];
                accv[2 * p + 1] += (float)w2[1] * (float)hv[2 * p + 1];
            }
        }
    }
    // in-quad reductions for denominators (accv needs none: quad owns its node serially)
#pragma unroll
    for (int off = 1; off < 16; off <<= 1) {
        s0 += __shfl_xor(s0, off, 64);
        s1 += __shfl_xor(s1, off, 64);
        s2 += __shfl_xor(s2, off, 64);
    }
    float d0 = 1.f / (s0 + 1e-16f);
    float d1 = 1.f / (s1 + 1e-16f);
    float d2 = 1.f / (s2 + 1e-16f);

    float4 bv0 = *(const float4*)(bias + cb);
    float4 bv1 = *(const float4*)(bias + cb + 4);
    float bb[8] = {bv0.x, bv0.y, bv0.z, bv0.w, bv1.x, bv1.y, bv1.z, bv1.w};
    float o[8];
#pragma unroll
    for (int j = 0; j < 8; ++j) {
        float dv = bm0[j] ? d0 : (bm1[j] ? d1 : d2);
        o[j] = accv[j] * dv + bb[j];
        if (ACT) o[j] = lrelu(o[j]);
    }
    float o128 = 0.f;
    if (q == 0) {
        o128 = acc128 * d2 + bias[128];
        if (ACT) o128 = lrelu(o128);
    }
    if (!L2EPI) {
        if (active) {
            half8 oh;
#pragma unroll
            for (int j = 0; j < 8; ++j) oh[j] = (_Float16)o[j];
            *(half8*)(Omh + ((size_t)wid << 7) + cb) = oh;
            if (q == 0) Ol[wid] = o128;
        }
    } else {
        float pr[OUTC];
#pragma unroll
        for (int c = 0; c < OUTC; ++c) pr[c] = 0.f;
#pragma unroll
        for (int j = 0; j < 8; ++j) {
            const float* wr = W2 + (cb + j) * OUTC;
            float ov = o[j];
#pragma unroll
            for (int c = 0; c < OUTC; ++c) pr[c] += ov * wr[c];
        }
        if (q == 0) {
#pragma unroll
            for (int c = 0; c < OUTC; ++c) pr[c] += o128 * W2[128 * OUTC + c];
        }
#pragma unroll
        for (int off = 1; off < 16; off <<= 1)
#pragma unroll
            for (int c = 0; c < OUTC; ++c) pr[c] += __shfl_xor(pr[c], off, 64);
        if (active && q == 0) {
            float sl = 0.f, sr = 0.f;
#pragma unroll
            for (int c = 0; c < OUTC; ++c) {
                H2[wid * OUTC + c] = pr[c];
                sl += pr[c] * a2s[c];
                sr += pr[c] * a2d[c];
            }
            al2[wid] = sl;
            ar2[wid] = sr;
        }
    }
}

// ---------------- layer 2 aggregate: 8 lanes per node, 8 nodes per wave ----------------
__global__ void agg6_kernel(const float* __restrict__ H2, const float* __restrict__ al2,
                            const float* __restrict__ ar2, const int* __restrict__ rowp,
                            const unsigned short* __restrict__ srcs, const float* __restrict__ b2,
                            float* __restrict__ out) {
    __shared__ float2 exs[4][8][9];   // 72B group stride -> disjoint bank pairs
    int lane = threadIdx.x & 63;
    int wv   = threadIdx.x >> 6;
    int g8   = lane >> 3;      // node slot within wave
    int c    = lane & 7;       // lane within group (channels 0..5 used)
    int wid  = ((blockIdx.x * 4 + wv) << 3) + g8;
    bool active = wid < N_NODES;
    int widc = active ? wid : 0;
    int beg = 0, end = 0;
    if (active) { beg = rowp[wid]; end = rowp[wid + 1]; }
    float ard = ar2[widc];
    int cc = (c < OUTC) ? c : 0;
    float ssum = 0.f, acc = 0.f;
    float2* exq = exs[wv][g8];
    for (int base = beg; base < end; base += 8) {
        int i = base + c;
        float ex = 0.f;
        int s = 0;
        if (i < end) {
            s = (int)srcs[i];
            ex = __expf(lrelu(al2[s] + ard));
            ssum += ex;
        }
        exq[c] = make_float2(ex, __int_as_float(s));
        int cnt = end - base; if (cnt > 8) cnt = 8;
        int t = 0;
        for (; t + 1 < cnt; t += 2) {
            float2 eda = exq[t];
            float2 edb = exq[t + 1];
            int sa = __float_as_int(eda.y);
            int sb = __float_as_int(edb.y);
            float ha = H2[sa * OUTC + cc];
            float hb = H2[sb * OUTC + cc];
            acc += eda.x * ha + edb.x * hb;
        }
        if (t < cnt) {
            float2 ed = exq[t];
            int ss = __float_as_int(ed.y);
            acc += ed.x * H2[ss * OUTC + cc];
        }
    }
#pragma unroll
    for (int off = 1; off < 8; off <<= 1) ssum += __shfl_xor(ssum, off, 64);
    float dinv = 1.f / (ssum + 1e-16f);
    if (active && c < OUTC) out[(size_t)wid * OUTC + c] = acc * dinv + b2[c];
}

// ---------------- launch ----------------

extern "C" void kernel_launch(void* const* d_in, const int* in_sizes, int n_in,
                              void* d_out, int out_size, void* d_ws, size_t ws_size,
                              hipStream_t stream) {
    const float* x   = (const float*)d_in[0];
    const int*   ei  = (const int*)d_in[1];
    const float* W0  = (const float*)d_in[2];
    const float* a0s = (const float*)d_in[3];
    const float* a0d = (const float*)d_in[4];
    const float* b0  = (const float*)d_in[5];
    const float* W1  = (const float*)d_in[6];
    const float* a1s = (const float*)d_in[7];
    const float* a1d = (const float*)d_in[8];
    const float* b1  = (const float*)d_in[9];
    const float* W2  = (const float*)d_in[10];
    const float* a2s = (const float*)d_in[11];
    const float* a2d = (const float*)d_in[12];
    const float* b2  = (const float*)d_in[13];
    float* out = (float*)d_out;

    char* p = (char*)d_ws;
    auto take = [&](size_t bytes) -> void* {
        void* r = (void*)p;
        p += (bytes + 255) & ~(size_t)255;
        return r;
    };
    int*            ccnt     = (int*)take((size_t)NB * 4);
    int*            cbase    = (int*)take((size_t)(NB + 1) * 4);
    int*            ccur     = (int*)take((size_t)NB * 4);
    unsigned int*   cval     = (unsigned int*)take((size_t)ET * 4);
    int*            rowp     = (int*)take((size_t)(N_NODES + 1) * 4);
    unsigned short* csr_src  = (unsigned short*)take((size_t)ET * 2);
    float*          al4      = (float*)take((size_t)N_NODES * 4 * 4);
    float*          ar4      = (float*)take((size_t)N_NODES * 4 * 4);
    _Float16*       Hm16     = (_Float16*)take((size_t)N_NODES * 128 * 2);
    _Float16*       Omh      = (_Float16*)take((size_t)N_NODES * 128 * 2);
    float*          Hl       = (float*)take((size_t)N_NODES * 4);
    float*          Ol       = (float*)take((size_t)N_NODES * 4);
    _Float16*       Wt0      = (_Float16*)take((size_t)144 * 128 * 2);
    _Float16*       Wt1      = (_Float16*)take((size_t)144 * 128 * 2);
    float*          w128row1 = (float*)take((size_t)144 * 4);
    float*          H2       = (float*)take((size_t)N_NODES * OUTC * 4);
    float*          al2      = (float*)take((size_t)N_NODES * 4);
    float*          ar2      = (float*)take((size_t)N_NODES * 4);

    const int* esrc = ei;
    const int* edst = ei + N_EDGES;

    // CSR build (two-phase bin sort)
    hipMemsetAsync(ccnt, 0, (size_t)NB * 4, stream);
    const int cgrid = (ET + CT - 1) / CT;
    ccount_kernel<<<cgrid, 256, 0, stream>>>(edst, ccnt);
    cscan_kernel<<<1, 256, 0, stream>>>(ccnt, cbase, ccur);
    cscatter_kernel<<<cgrid, 256, 0, stream>>>(esrc, edst, ccur, cval);
    fine_kernel<<<NB, 512, 0, stream>>>(cval, cbase, rowp, csr_src);

    padw_kernel<<<(2 * 144 * 128 + 144 + 255) / 256, 256, 0, stream>>>(
        W0, a0s, a0d, W1, a1s, a1d, Wt0, Wt1, w128row1);

    const dim3 gemm_grid((N_NODES / 16 + 3) / 4, 3);
    const int  agg129_grid = (N_NODES + 15) / 16;
    const int  agg6_grid   = (N_NODES + 31) / 32;

    // layer 0
    gemm_mfma_kernel<true, false><<<gemm_grid, 256, 0, stream>>>(
        x, (const _Float16*)nullptr, Ol, Wt0, w128row1, Hm16, Hl, al4, ar4);
    agg129_kernel<true, false><<<agg129_grid, 256, 0, stream>>>(
        Hm16, Hl, al4, ar4, rowp, csr_src, b0, Omh, Ol,
        nullptr, nullptr, nullptr, nullptr, nullptr, nullptr);

    // layer 1 (layer-2 node GEMM fused into epilogue)
    gemm_mfma_kernel<false, true><<<gemm_grid, 256, 0, stream>>>(
        (const float*)nullptr, Omh, Ol, Wt1, w128row1, Hm16, Hl, al4, ar4);
    agg129_kernel<true, true><<<agg129_grid, 256, 0, stream>>>(
        Hm16, Hl, al4, ar4, rowp, csr_src, b1, (_Float16*)nullptr, (float*)nullptr,
        W2, a2s, a2d, H2, al2, ar2);

    // layer 2 aggregate
    agg6_kernel<<<agg6_grid, 256, 0, stream>>>(H2, al2, ar2, rowp, csr_src, b2, out);
}

// Round 14
// 262.348 us; speedup vs baseline: 1.1440x; 1.0435x over previous
//
#include <hip/hip_runtime.h>

#define N_NODES 50000
#define N_EDGES 800000
#define ET (N_EDGES + N_NODES)   // edges + self loops = 850000
#define MID 129
#define OUTC 6
#define NB 196                   // coarse buckets: dst >> 8
#define CT 4096                  // edges per coarse-scatter block
#define CGRID ((ET + CT - 1) / CT)        // 208
#define MTB ((N_NODES / 16 + 3) / 4)      // 782 gemm m-tiles per n-slice
#define PADW_BLOCKS ((2 * 144 * 128 + 144 + 255) / 256)   // 145

typedef _Float16 half2v __attribute__((ext_vector_type(2)));
typedef _Float16 half8  __attribute__((ext_vector_type(8)));
typedef float    floatx4 __attribute__((ext_vector_type(4)));

__device__ __forceinline__ float lrelu(float x) { return fmaxf(x, 0.2f * x); }

// ---------------- padw body (device) ----------------
__device__ __forceinline__ void padw_body(int i, const float* __restrict__ W0,
                                          const float* __restrict__ a0s, const float* __restrict__ a0d,
                                          const float* __restrict__ W1, const float* __restrict__ a1s,
                                          const float* __restrict__ a1d, _Float16* __restrict__ Wt0,
                                          _Float16* __restrict__ Wt1, float* __restrict__ w128row1) {
    const int SEG = 144 * 128;
    if (i < 2 * SEG) {
        int l = i / SEG;
        int ii = i - l * SEG;
        int n = ii >> 7, k = ii & 127;
        const float* W = l ? W1 : W0;
        const float* as = l ? a1s : a0s;
        const float* ad = l ? a1d : a0d;
        float v = 0.f;
        if (n < 129) v = W[k * MID + n];
        else if (n < 132) {
            int h = n - 129;
            float sum = 0.f;
            for (int c = 0; c < 43; ++c) sum += W[k * MID + 43 * h + c] * as[43 * h + c];
            v = sum;
        } else if (n < 135) {
            int h = n - 132;
            float sum = 0.f;
            for (int c = 0; c < 43; ++c) sum += W[k * MID + 43 * h + c] * ad[43 * h + c];
            v = sum;
        }
        (l ? Wt1 : Wt0)[i - l * SEG] = (_Float16)v;
    } else if (i < 2 * SEG + 144) {
        int n = i - 2 * SEG;
        float v = 0.f;
        if (n < 129) v = W1[128 * MID + n];
        else if (n < 132) {
            int h = n - 129;
            float sum = 0.f;
            for (int c = 0; c < 43; ++c) sum += W1[128 * MID + 43 * h + c] * a1s[43 * h + c];
            v = sum;
        } else if (n < 135) {
            int h = n - 132;
            float sum = 0.f;
            for (int c = 0; c < 43; ++c) sum += W1[128 * MID + 43 * h + c] * a1d[43 * h + c];
            v = sum;
        }
        w128row1[n] = v;
    }
}

// ---------------- fused: coarse count (blocks [0,CGRID)) + padw (rest) ----------------
__global__ __launch_bounds__(256)
void fused_count_padw_kernel(const int* __restrict__ dst, int* __restrict__ ccnt,
                             const float* __restrict__ W0, const float* __restrict__ a0s,
                             const float* __restrict__ a0d, const float* __restrict__ W1,
                             const float* __restrict__ a1s, const float* __restrict__ a1d,
                             _Float16* __restrict__ Wt0, _Float16* __restrict__ Wt1,
                             float* __restrict__ w128row1) {
    if ((int)blockIdx.x < CGRID) {
        __shared__ int lh[NB];
        for (int i = threadIdx.x; i < NB; i += 256) lh[i] = 0;
        __syncthreads();
        int base = blockIdx.x * CT;
#pragma unroll 4
        for (int j = 0; j < CT; j += 256) {
            int e = base + j + threadIdx.x;
            if (e < ET) {
                int d = (e < N_EDGES) ? dst[e] : (e - N_EDGES);
                atomicAdd(&lh[d >> 8], 1);
            }
        }
        __syncthreads();
        for (int i = threadIdx.x; i < NB; i += 256) {
            int v = lh[i];
            if (v) atomicAdd(&ccnt[i], v);
        }
    } else {
        int i = ((int)blockIdx.x - CGRID) * 256 + threadIdx.x;
        padw_body(i, W0, a0s, a0d, W1, a1s, a1d, Wt0, Wt1, w128row1);
    }
}

__global__ void cscan_kernel(const int* __restrict__ ccnt, int* __restrict__ cbase,
                             int* __restrict__ ccur) {
    __shared__ int buf[256];
    int t = threadIdx.x;
    buf[t] = (t < NB) ? ccnt[t] : 0;
    __syncthreads();
    for (int off = 1; off < 256; off <<= 1) {
        int v = (t >= off) ? buf[t - off] : 0;
        __syncthreads();
        buf[t] += v;
        __syncthreads();
    }
    int excl = t ? buf[t - 1] : 0;
    if (t < NB) { cbase[t] = excl; ccur[t] = excl; }
    if (t == NB - 1) cbase[NB] = buf[t];
}

// ---------------- MFMA GEMM body (device) ----------------
template <bool SRC32, bool RANK1>
__device__ __forceinline__ void gemm_body(int mtb, int nyb, int tid,
                                          const float* __restrict__ X32,
                                          const _Float16* __restrict__ Xh,
                                          const float* __restrict__ Xl,
                                          const _Float16* __restrict__ Wt,
                                          const float* __restrict__ w128,
                                          _Float16* __restrict__ Hm16, float* __restrict__ Hl,
                                          float* __restrict__ al4, float* __restrict__ ar4) {
    int wave = tid >> 6, lane = tid & 63;
    int mt = mtb * 4 + wave;
    if (mt * 16 >= N_NODES) return;
    int t = lane & 15, quad = lane >> 4;
    int row0 = mt * 16;

    half8 af[4];
    if (SRC32) {
        const float* arow = X32 + ((size_t)(row0 + t) << 7) + quad * 8;
#pragma unroll
        for (int kt = 0; kt < 4; ++kt) {
            float4 a0 = *(const float4*)(arow + kt * 32);
            float4 a1 = *(const float4*)(arow + kt * 32 + 4);
            half8 h;
            h[0] = (_Float16)a0.x; h[1] = (_Float16)a0.y;
            h[2] = (_Float16)a0.z; h[3] = (_Float16)a0.w;
            h[4] = (_Float16)a1.x; h[5] = (_Float16)a1.y;
            h[6] = (_Float16)a1.z; h[7] = (_Float16)a1.w;
            af[kt] = h;
        }
    } else {
        const _Float16* arow = Xh + ((size_t)(row0 + t) << 7) + quad * 8;
#pragma unroll
        for (int kt = 0; kt < 4; ++kt) af[kt] = *(const half8*)(arow + kt * 32);
    }

    floatx4 acc[3];
#pragma unroll
    for (int nt = 0; nt < 3; ++nt) {
        int ntile = nyb * 3 + nt;
        const _Float16* brow = Wt + ((size_t)(ntile * 16 + t) << 7) + quad * 8;
        floatx4 a = {0.f, 0.f, 0.f, 0.f};
#pragma unroll
        for (int kt = 0; kt < 4; ++kt) {
            half8 b = *(const half8*)(brow + kt * 32);
            a = __builtin_amdgcn_mfma_f32_16x16x32_f16(af[kt], b, a, 0, 0, 0);
        }
        acc[nt] = a;
    }

#pragma unroll
    for (int r = 0; r < 4; ++r) {
        int row = row0 + quad * 4 + r;
        float xl = RANK1 ? Xl[row] : 0.f;
#pragma unroll
        for (int nt = 0; nt < 3; ++nt) {
            int n = (nyb * 3 + nt) * 16 + t;
            float v = acc[nt][r];
            if (RANK1) v += xl * w128[n];
            if (n < 128) {
                Hm16[((size_t)row << 7) + n] = (_Float16)v;
            } else if (n == 128) {
                Hl[row] = v;
            } else if (n < 132) {
                al4[row * 4 + (n - 129)] = v;
            } else if (n < 135) {
                ar4[row * 4 + (n - 132)] = v;
            }
        }
    }
}

// ---------------- fused: coarse scatter (blocks [0,CGRID)) + layer-0 GEMM (rest) ----------------
__global__ __launch_bounds__(256)
void fused_scatter_gemm0_kernel(const int* __restrict__ src, const int* __restrict__ dst,
                                int* __restrict__ ccur, unsigned int* __restrict__ cval,
                                const float* __restrict__ X32, const _Float16* __restrict__ Wt0,
                                _Float16* __restrict__ Hm16, float* __restrict__ Hl,
                                float* __restrict__ al4, float* __restrict__ ar4) {
    if ((int)blockIdx.x < CGRID) {
        __shared__ unsigned int staged[CT];
        __shared__ int lh[NB], lex[NB], lcur[NB], lgb[NB];
        __shared__ int sbuf[256];
        int tid = threadIdx.x;
        for (int i = tid; i < NB; i += 256) lh[i] = 0;
        __syncthreads();
        int base = blockIdx.x * CT;
        unsigned int myv[16];
        int myb[16];
        int myn = 0;
#pragma unroll
        for (int j = 0; j < 16; ++j) {
            int e = base + j * 256 + tid;
            if (e < ET) {
                int s, d;
                if (e < N_EDGES) { s = src[e]; d = dst[e]; }
                else             { s = d = e - N_EDGES; }
                int b = d >> 8;
                myv[j] = ((unsigned)b << 24) | ((unsigned)(d & 255) << 16) | (unsigned)s;
                myb[j] = b;
                atomicAdd(&lh[b], 1);
                myn = j + 1;
            }
        }
        __syncthreads();
        sbuf[tid] = (tid < NB) ? lh[tid] : 0;
        __syncthreads();
        for (int off = 1; off < 256; off <<= 1) {
            int v = (tid >= off) ? sbuf[tid - off] : 0;
            __syncthreads();
            sbuf[tid] += v;
            __syncthreads();
        }
        if (tid < NB) {
            int excl = tid ? sbuf[tid - 1] : 0;
            lex[tid] = excl;
            lcur[tid] = excl;
        }
        __syncthreads();
        for (int j = 0; j < myn; ++j) {
            int p = atomicAdd(&lcur[myb[j]], 1);
            staged[p] = myv[j];
        }
        __syncthreads();
        if (tid < NB) {
            int c = lh[tid];
            lgb[tid] = c ? atomicAdd(&ccur[tid], c) : 0;
        }
        __syncthreads();
        int tot = ET - base; if (tot > CT) tot = CT;
        for (int i = tid; i < tot; i += 256) {
            unsigned int v = staged[i];
            int b = v >> 24;
            cval[lgb[b] + (i - lex[b])] = v;
        }
    } else {
        int b = (int)blockIdx.x - CGRID;
        int nyb = b / MTB;
        int mtb = b - nyb * MTB;
        gemm_body<true, false>(mtb, nyb, threadIdx.x, X32, nullptr, nullptr,
                               Wt0, nullptr, Hm16, Hl, al4, ar4);
    }
}

__global__ __launch_bounds__(512)
void fine_kernel(const unsigned int* __restrict__ cval, const int* __restrict__ cbase,
                 int* __restrict__ rowp, unsigned short* __restrict__ csr_src) {
    __shared__ int h[256], cur[256], sb[256];
    int b = blockIdx.x;
    int beg = cbase[b], end = cbase[b + 1];
    int t = threadIdx.x;
    if (t < 256) h[t] = 0;
    __syncthreads();
    for (int i = beg + t; i < end; i += 512)
        atomicAdd(&h[(cval[i] >> 16) & 255], 1);
    __syncthreads();
    if (t < 256) sb[t] = h[t];
    __syncthreads();
    for (int off = 1; off < 256; off <<= 1) {
        int v = 0;
        if (t < 256 && t >= off) v = sb[t - off];
        __syncthreads();
        if (t < 256) sb[t] += v;
        __syncthreads();
    }
    if (t < 256) {
        int excl = t ? sb[t - 1] : 0;
        cur[t] = excl;
        int dstv = (b << 8) + t;
        if (dstv <= N_NODES) rowp[dstv] = beg + excl;
    }
    __syncthreads();
    for (int i = beg + t; i < end; i += 512) {
        unsigned int v = cval[i];
        int low = (v >> 16) & 255;
        int p = atomicAdd(&cur[low], 1);
        csr_src[beg + p] = (unsigned short)(v & 0xFFFFu);
    }
}

// ---------------- layer-1 GEMM wrapper ----------------
__global__ __launch_bounds__(256)
void gemm1_kernel(const _Float16* __restrict__ Xh, const float* __restrict__ Xl,
                  const _Float16* __restrict__ Wt, const float* __restrict__ w128,
                  _Float16* __restrict__ Hm16, float* __restrict__ Hl,
                  float* __restrict__ al4, float* __restrict__ ar4) {
    gemm_body<false, true>(blockIdx.x, blockIdx.y, threadIdx.x, nullptr, Xh, Xl,
                           Wt, w128, Hm16, Hl, al4, ar4);
}

// ------- fused softmax + aggregation (129 ch, 3 heads) -------
// 16 lanes per node, 4 nodes per wave; consume loop unrolled x4.
template <bool ACT, bool L2EPI>
__global__ void agg129_kernel(const _Float16* __restrict__ Hm16, const float* __restrict__ Hl,
                              const float* __restrict__ al4, const float* __restrict__ ar4,
                              const int* __restrict__ rowp, const unsigned short* __restrict__ srcs,
                              const float* __restrict__ bias, _Float16* __restrict__ Omh,
                              float* __restrict__ Ol,
                              const float* __restrict__ W2, const float* __restrict__ a2s,
                              const float* __restrict__ a2d, float* __restrict__ H2,
                              float* __restrict__ al2, float* __restrict__ ar2) {
    __shared__ float4 exs[4][4][17];
    int lane = threadIdx.x & 63;
    int wv   = threadIdx.x >> 6;
    int qd   = lane >> 4;
    int q    = lane & 15;
    int wid  = ((blockIdx.x * 4 + wv) << 2) + qd;
    bool active = wid < N_NODES;
    int widc = active ? wid : 0;

    int beg = 0, end = 0;
    if (active) { beg = rowp[wid]; end = rowp[wid + 1]; }
    float4 arv = *(const float4*)(ar4 + (size_t)widc * 4);
    float ard0 = arv.x, ard1 = arv.y, ard2 = arv.z;

    int cb = 8 * q;
    bool bm0[8], bm1[8];
#pragma unroll
    for (int j = 0; j < 8; ++j) {
        bm0[j] = (cb + j) < 43;
        bm1[j] = (cb + j) < 86;
    }
    unsigned selv[4];
#pragma unroll
    for (int p = 0; p < 4; ++p) {
        int c0 = cb + 2 * p, c1 = c0 + 1;
        int l0 = (c0 < 43) ? 4 : (c0 < 86) ? 6 : 0;
        int l1 = (c1 < 43) ? 4 : (c1 < 86) ? 6 : 0;
        selv[p] = (unsigned)l0 | ((unsigned)(l0 + 1) << 8) |
                  ((unsigned)l1 << 16) | ((unsigned)(l1 + 1) << 24);
    }

    float accv[8];
#pragma unroll
    for (int j = 0; j < 8; ++j) accv[j] = 0.f;
    float acc128 = 0.f;
    float s0 = 0.f, s1 = 0.f, s2 = 0.f;
    float4* exq = exs[wv][qd];

    for (int base = beg; base < end; base += 16) {
        int i = base + q;
        float e0 = 0.f, e1 = 0.f, e2 = 0.f;
        int s = 0;
        if (i < end) {
            s = (int)srcs[i];
            float4 av = *(const float4*)(al4 + (size_t)s * 4);
            e0 = __expf(lrelu(av.x + ard0));
            e1 = __expf(lrelu(av.y + ard1));
            e2 = __expf(lrelu(av.z + ard2));
            s0 += e0; s1 += e1; s2 += e2;
        }
        exq[q] = make_float4(e0, e1, e2, __int_as_float(s));
        int cnt = end - base; if (cnt > 16) cnt = 16;
        int t = 0;
        for (; t + 3 < cnt; t += 4) {
            float4 ed[4];
            int sx[4];
            half8 hv[4];
#pragma unroll
            for (int u = 0; u < 4; ++u) ed[u] = exq[t + u];
#pragma unroll
            for (int u = 0; u < 4; ++u) {
                sx[u] = __float_as_int(ed[u].w);
                hv[u] = *(const half8*)(Hm16 + ((size_t)sx[u] << 7) + cb);
            }
            if (q == 0) {
                acc128 += ed[0].z * Hl[sx[0]];
                acc128 += ed[1].z * Hl[sx[1]];
                acc128 += ed[2].z * Hl[sx[2]];
                acc128 += ed[3].z * Hl[sx[3]];
            }
#pragma unroll
            for (int u = 0; u < 4; ++u) {
                unsigned p01 = __builtin_bit_cast(unsigned, __builtin_amdgcn_cvt_pkrtz(ed[u].x, ed[u].y));
                unsigned p2z = __builtin_bit_cast(unsigned, __builtin_amdgcn_cvt_pkrtz(ed[u].z, ed[u].z));
#pragma unroll
                for (int p = 0; p < 4; ++p) {
                    unsigned wp = __builtin_amdgcn_perm(p01, p2z, selv[p]);
                    half2v w2 = __builtin_bit_cast(half2v, wp);
                    accv[2 * p]     += (float)w2[0] * (float)hv[u][2 * p];
                    accv[2 * p + 1] += (float)w2[1] * (float)hv[u][2 * p + 1];
                }
            }
        }
        for (; t < cnt; ++t) {
            float4 ed = exq[t];
            int ss = __float_as_int(ed.w);
            half8 hv = *(const half8*)(Hm16 + ((size_t)ss << 7) + cb);
            if (q == 0) acc128 += ed.z * Hl[ss];
            unsigned p01 = __builtin_bit_cast(unsigned, __builtin_amdgcn_cvt_pkrtz(ed.x, ed.y));
            unsigned p2z = __builtin_bit_cast(unsigned, __builtin_amdgcn_cvt_pkrtz(ed.z, ed.z));
#pragma unroll
            for (int p = 0; p < 4; ++p) {
                unsigned wp = __builtin_amdgcn_perm(p01, p2z, selv[p]);
                half2v w2 = __builtin_bit_cast(half2v, wp);
                accv[2 * p]     += (float)w2[0] * (float)hv[2 * p];
                accv[2 * p + 1] += (float)w2[1] * (float)hv[2 * p + 1];
            }
        }
    }
#pragma unroll
    for (int off = 1; off < 16; off <<= 1) {
        s0 += __shfl_xor(s0, off, 64);
        s1 += __shfl_xor(s1, off, 64);
        s2 += __shfl_xor(s2, off, 64);
    }
    float d0 = 1.f / (s0 + 1e-16f);
    float d1 = 1.f / (s1 + 1e-16f);
    float d2 = 1.f / (s2 + 1e-16f);

    float4 bv0 = *(const float4*)(bias + cb);
    float4 bv1 = *(const float4*)(bias + cb + 4);
    float bb[8] = {bv0.x, bv0.y, bv0.z, bv0.w, bv1.x, bv1.y, bv1.z, bv1.w};
    float o[8];
#pragma unroll
    for (int j = 0; j < 8; ++j) {
        float dv = bm0[j] ? d0 : (bm1[j] ? d1 : d2);
        o[j] = accv[j] * dv + bb[j];
        if (ACT) o[j] = lrelu(o[j]);
    }
    float o128 = 0.f;
    if (q == 0) {
        o128 = acc128 * d2 + bias[128];
        if (ACT) o128 = lrelu(o128);
    }
    if (!L2EPI) {
        if (active) {
            half8 oh;
#pragma unroll
            for (int j = 0; j < 8; ++j) oh[j] = (_Float16)o[j];
            *(half8*)(Omh + ((size_t)wid << 7) + cb) = oh;
            if (q == 0) Ol[wid] = o128;
        }
    } else {
        float pr[OUTC];
#pragma unroll
        for (int c = 0; c < OUTC; ++c) pr[c] = 0.f;
#pragma unroll
        for (int j = 0; j < 8; ++j) {
            const float* wr = W2 + (cb + j) * OUTC;
            float ov = o[j];
#pragma unroll
            for (int c = 0; c < OUTC; ++c) pr[c] += ov * wr[c];
        }
        if (q == 0) {
#pragma unroll
            for (int c = 0; c < OUTC; ++c) pr[c] += o128 * W2[128 * OUTC + c];
        }
#pragma unroll
        for (int off = 1; off < 16; off <<= 1)
#pragma unroll
            for (int c = 0; c < OUTC; ++c) pr[c] += __shfl_xor(pr[c], off, 64);
        if (active && q == 0) {
            float sl = 0.f, sr = 0.f;
#pragma unroll
            for (int c = 0; c < OUTC; ++c) {
                H2[wid * OUTC + c] = pr[c];
                sl += pr[c] * a2s[c];
                sr += pr[c] * a2d[c];
            }
            al2[wid] = sl;
            ar2[wid] = sr;
        }
    }
}

// ---------------- layer 2 aggregate: 8 lanes per node, 8 nodes per wave ----------------
__global__ void agg6_kernel(const float* __restrict__ H2, const float* __restrict__ al2,
                            const float* __restrict__ ar2, const int* __restrict__ rowp,
                            const unsigned short* __restrict__ srcs, const float* __restrict__ b2,
                            float* __restrict__ out) {
    __shared__ float2 exs[4][8][9];
    int lane = threadIdx.x & 63;
    int wv   = threadIdx.x >> 6;
    int g8   = lane >> 3;
    int c    = lane & 7;
    int wid  = ((blockIdx.x * 4 + wv) << 3) + g8;
    bool active = wid < N_NODES;
    int widc = active ? wid : 0;
    int beg = 0, end = 0;
    if (active) { beg = rowp[wid]; end = rowp[wid + 1]; }
    float ard = ar2[widc];
    int cc = (c < OUTC) ? c : 0;
    float ssum = 0.f, acc = 0.f;
    float2* exq = exs[wv][g8];
    for (int base = beg; base < end; base += 8) {
        int i = base + c;
        float ex = 0.f;
        int s = 0;
        if (i < end) {
            s = (int)srcs[i];
            ex = __expf(lrelu(al2[s] + ard));
            ssum += ex;
        }
        exq[c] = make_float2(ex, __int_as_float(s));
        int cnt = end - base; if (cnt > 8) cnt = 8;
        int t = 0;
        for (; t + 1 < cnt; t += 2) {
            float2 eda = exq[t];
            float2 edb = exq[t + 1];
            int sa = __float_as_int(eda.y);
            int sb = __float_as_int(edb.y);
            float ha = H2[sa * OUTC + cc];
            float hb = H2[sb * OUTC + cc];
            acc += eda.x * ha + edb.x * hb;
        }
        if (t < cnt) {
            float2 ed = exq[t];
            int ss = __float_as_int(ed.y);
            acc += ed.x * H2[ss * OUTC + cc];
        }
    }
#pragma unroll
    for (int off = 1; off < 8; off <<= 1) ssum += __shfl_xor(ssum, off, 64);
    float dinv = 1.f / (ssum + 1e-16f);
    if (active && c < OUTC) out[(size_t)wid * OUTC + c] = acc * dinv + b2[c];
}

// ---------------- launch ----------------

extern "C" void kernel_launch(void* const* d_in, const int* in_sizes, int n_in,
                              void* d_out, int out_size, void* d_ws, size_t ws_size,
                              hipStream_t stream) {
    const float* x   = (const float*)d_in[0];
    const int*   ei  = (const int*)d_in[1];
    const float* W0  = (const float*)d_in[2];
    const float* a0s = (const float*)d_in[3];
    const float* a0d = (const float*)d_in[4];
    const float* b0  = (const float*)d_in[5];
    const float* W1  = (const float*)d_in[6];
    const float* a1s = (const float*)d_in[7];
    const float* a1d = (const float*)d_in[8];
    const float* b1  = (const float*)d_in[9];
    const float* W2  = (const float*)d_in[10];
    const float* a2s = (const float*)d_in[11];
    const float* a2d = (const float*)d_in[12];
    const float* b2  = (const float*)d_in[13];
    float* out = (float*)d_out;

    char* p = (char*)d_ws;
    auto take = [&](size_t bytes) -> void* {
        void* r = (void*)p;
        p += (bytes + 255) & ~(size_t)255;
        return r;
    };
    int*            ccnt     = (int*)take((size_t)NB * 4);
    int*            cbase    = (int*)take((size_t)(NB + 1) * 4);
    int*            ccur     = (int*)take((size_t)NB * 4);
    unsigned int*   cval     = (unsigned int*)take((size_t)ET * 4);
    int*            rowp     = (int*)take((size_t)(N_NODES + 1) * 4);
    unsigned short* csr_src  = (unsigned short*)take((size_t)ET * 2);
    float*          al4      = (float*)take((size_t)N_NODES * 4 * 4);
    float*          ar4      = (float*)take((size_t)N_NODES * 4 * 4);
    _Float16*       Hm16     = (_Float16*)take((size_t)N_NODES * 128 * 2);
    _Float16*       Omh      = (_Float16*)take((size_t)N_NODES * 128 * 2);
    float*          Hl       = (float*)take((size_t)N_NODES * 4);
    float*          Ol       = (float*)take((size_t)N_NODES * 4);
    _Float16*       Wt0      = (_Float16*)take((size_t)144 * 128 * 2);
    _Float16*       Wt1      = (_Float16*)take((size_t)144 * 128 * 2);
    float*          w128row1 = (float*)take((size_t)144 * 4);
    float*          H2       = (float*)take((size_t)N_NODES * OUTC * 4);
    float*          al2      = (float*)take((size_t)N_NODES * 4);
    float*          ar2      = (float*)take((size_t)N_NODES * 4);

    const int* esrc = ei;
    const int* edst = ei + N_EDGES;

    hipMemsetAsync(ccnt, 0, (size_t)NB * 4, stream);

    // fused: coarse count + weight prep
    fused_count_padw_kernel<<<CGRID + PADW_BLOCKS, 256, 0, stream>>>(
        edst, ccnt, W0, a0s, a0d, W1, a1s, a1d, Wt0, Wt1, w128row1);
    cscan_kernel<<<1, 256, 0, stream>>>(ccnt, cbase, ccur);

    // fused: coarse scatter + layer-0 MFMA GEMM (independent work, co-scheduled)
    fused_scatter_gemm0_kernel<<<CGRID + MTB * 3, 256, 0, stream>>>(
        esrc, edst, ccur, cval, x, Wt0, Hm16, Hl, al4, ar4);
    fine_kernel<<<NB, 512, 0, stream>>>(cval, cbase, rowp, csr_src);

    const int agg129_grid = (N_NODES + 15) / 16;
    const int agg6_grid   = (N_NODES + 31) / 32;

    // layer 0 aggregate
    agg129_kernel<true, false><<<agg129_grid, 256, 0, stream>>>(
        Hm16, Hl, al4, ar4, rowp, csr_src, b0, Omh, Ol,
        nullptr, nullptr, nullptr, nullptr, nullptr, nullptr);

    // layer 1 (layer-2 node GEMM fused into epilogue)
    gemm1_kernel<<<dim3(MTB, 3), 256, 0, stream>>>(Omh, Ol, Wt1, w128row1, Hm16, Hl, al4, ar4);
    agg129_kernel<true, true><<<agg129_grid, 256, 0, stream>>>(
        Hm16, Hl, al4, ar4, rowp, csr_src, b1, (_Float16*)nullptr, (float*)nullptr,
        W2, a2s, a2d, H2, al2, ar2);

    // layer 2 aggregate
    agg6_kernel<<<agg6_grid, 256, 0, stream>>>(H2, al2, ar2, rowp, csr_src, b2, out);
}